// Round 1
// baseline (352.325 us; speedup 1.0000x reference)
//
#include <hip/hip_runtime.h>

// Problem constants
constexpr int kB  = 16;    // batch
constexpr int kC  = 16;    // CI == CO
constexpr int kM  = 6;     // M1 == M2 == M3
constexpr int kNT = 39;
constexpr int kNX = 14;    // NXr
constexpr int kNY = 14;    // NYr
constexpr int kNS = kNX * kNY;       // 196
constexpr int kNF = kNT * kNS;       // 7644
constexpr int kNIK = kC * kC;        // 256
constexpr int kMR = kM * kM * kM;    // 216

__device__ __forceinline__ float2 cmul(float2 a, float2 b) {
    return make_float2(a.x * b.x - a.y * b.y, a.x * b.y + a.y * b.x);
}
__device__ __forceinline__ void cfma(float2& c, float2 a, float2 b) {
    c.x = fmaf(a.x, b.x, fmaf(-a.y, b.y, c.x));
    c.y = fmaf(a.x, b.y, fmaf(a.y, b.x, c.y));
}

// ---------------------------------------------------------------------------
// K0: build DFT matrices + pole-reciprocal tables r1/r2/r3 + exp tables e1/e2/e3
// r1t[((i*16+k)*6+p)*39+m] = 1/(i*w1[m] - wp1[i,k,p])
// e1t[((i*16+k)*6+p)*39+z] = exp(wp1[i,k,p] * z)
// (r2t/e2t, r3t/e3t analogous with t = x/27)
// ---------------------------------------------------------------------------
__global__ __launch_bounds__(256) void k_init(
    const float* __restrict__ wp1_re, const float* __restrict__ wp1_im,
    const float* __restrict__ wp2_re, const float* __restrict__ wp2_im,
    const float* __restrict__ wp3_re, const float* __restrict__ wp3_im,
    float2* __restrict__ F39, float2* __restrict__ F14,
    float2* __restrict__ r1t, float2* __restrict__ r2t, float2* __restrict__ r3t,
    float2* __restrict__ e1t, float2* __restrict__ e2t, float2* __restrict__ e3t)
{
    const float PI2 = 6.283185307179586f;
    int tid = blockIdx.x * blockDim.x + threadIdx.x;
    int nth = gridDim.x * blockDim.x;

    for (int idx = tid; idx < kNT * kNT; idx += nth) {
        int m = idx / kNT, t = idx % kNT;
        float ang = -PI2 * (float)((m * t) % kNT) / (float)kNT;
        float s, c; sincosf(ang, &s, &c);
        F39[idx] = make_float2(c, s);
    }
    for (int idx = tid; idx < kNX * kNX; idx += nth) {
        int a = idx / kNX, b = idx % kNX;
        float ang = -PI2 * (float)((a * b) % kNX) / (float)kNX;
        float s, c; sincosf(ang, &s, &c);
        F14[idx] = make_float2(c, s);
    }
    // axis T tables
    for (int idx = tid; idx < kNIK * kM * kNT; idx += nth) {
        int z = idx % kNT; int ikp = idx / kNT;
        float wre = wp1_re[ikp], wim = wp1_im[ikp];
        float f = (z < 20 ? (float)z : (float)(z - kNT)) / (float)kNT;
        float w = PI2 * f;
        float dr = -wre, di = w - wim;
        float inv = 1.0f / (dr * dr + di * di);
        r1t[idx] = make_float2(dr * inv, -di * inv);
        float tt = (float)z;
        float er = expf(wre * tt);
        float s, c; sincosf(wim * tt, &s, &c);
        e1t[idx] = make_float2(er * c, er * s);
    }
    // axis X and Y tables (same grid spacing 1/27, length 14)
    for (int idx = tid; idx < kNIK * kM * kNX; idx += nth) {
        int n = idx % kNX; int ikq = idx / kNX;
        float f = (n <= 6 ? (float)n : (float)(n - kNX)) * 27.0f / 14.0f;
        float w = PI2 * f;
        float tx = (float)n * (1.0f / 27.0f);
        {
            float wre = wp2_re[ikq], wim = wp2_im[ikq];
            float dr = -wre, di = w - wim;
            float inv = 1.0f / (dr * dr + di * di);
            r2t[idx] = make_float2(dr * inv, -di * inv);
            float er = expf(wre * tx);
            float s, c; sincosf(wim * tx, &s, &c);
            e2t[idx] = make_float2(er * c, er * s);
        }
        {
            float wre = wp3_re[ikq], wim = wp3_im[ikq];
            float dr = -wre, di = w - wim;
            float inv = 1.0f / (dr * dr + di * di);
            r3t[idx] = make_float2(dr * inv, -di * inv);
            float er = expf(wre * tx);
            float s, c; sincosf(wim * tx, &s, &c);
            e3t[idx] = make_float2(er * c, er * s);
        }
    }
}

// ---------------------------------------------------------------------------
// DFT passes. Layout of all big complex buffers: [bc][m][n][l], bc in [0,256)
// ---------------------------------------------------------------------------
__global__ __launch_bounds__(256) void k_dft_t_real(
    const float* __restrict__ x, const float2* __restrict__ F39, float2* __restrict__ out)
{
    int bc = blockIdx.x, m = blockIdx.y;
    __shared__ float2 Fs[kNT];
    int t = threadIdx.x;
    if (t < kNT) Fs[t] = F39[m * kNT + t];
    __syncthreads();
    if (t < kNS) {
        const float* xp = x + (size_t)bc * kNF + t;
        float2 acc = make_float2(0.f, 0.f);
        #pragma unroll
        for (int tt = 0; tt < kNT; ++tt) {
            float v = xp[(size_t)tt * kNS];
            acc.x = fmaf(Fs[tt].x, v, acc.x);
            acc.y = fmaf(Fs[tt].y, v, acc.y);
        }
        out[((size_t)bc * kNT + m) * kNS + t] = acc;
    }
}

__global__ __launch_bounds__(256) void k_dft_t_cplx(
    const float2* __restrict__ in, const float2* __restrict__ F39,
    float2* __restrict__ out, int conjf)
{
    int bc = blockIdx.x, m = blockIdx.y;
    __shared__ float2 Fs[kNT];
    int t = threadIdx.x;
    if (t < kNT) { float2 f = F39[m * kNT + t]; if (conjf) f.y = -f.y; Fs[t] = f; }
    __syncthreads();
    if (t < kNS) {
        const float2* ip = in + (size_t)bc * kNF + t;
        float2 acc = make_float2(0.f, 0.f);
        #pragma unroll
        for (int tt = 0; tt < kNT; ++tt) cfma(acc, Fs[tt], ip[(size_t)tt * kNS]);
        out[((size_t)bc * kNT + m) * kNS + t] = acc;
    }
}

__global__ __launch_bounds__(256) void k_dft_x(
    const float2* __restrict__ in, const float2* __restrict__ F14,
    float2* __restrict__ out, int conjf)
{
    int bm = blockIdx.x;  // bc*39+m
    __shared__ float2 tile[kNS];
    __shared__ float2 Fs[kNX * kNX];
    int t = threadIdx.x;
    if (t < kNS) tile[t] = in[(size_t)bm * kNS + t];
    if (t < kNX * kNX) { float2 f = F14[t]; if (conjf) f.y = -f.y; Fs[t] = f; }
    __syncthreads();
    if (t < kNS) {
        int n2 = t / kNY, l = t % kNY;
        float2 acc = make_float2(0.f, 0.f);
        #pragma unroll
        for (int n = 0; n < kNX; ++n) cfma(acc, Fs[n2 * kNX + n], tile[n * kNY + l]);
        out[(size_t)bm * kNS + t] = acc;
    }
}

__global__ __launch_bounds__(256) void k_dft_y(
    const float2* __restrict__ in, const float2* __restrict__ F14,
    float2* __restrict__ out, int conjf)
{
    int bm = blockIdx.x;
    __shared__ float2 tile[kNS];
    __shared__ float2 Fs[kNY * kNY];
    int t = threadIdx.x;
    if (t < kNS) tile[t] = in[(size_t)bm * kNS + t];
    if (t < kNY * kNY) { float2 f = F14[t]; if (conjf) f.y = -f.y; Fs[t] = f; }
    __syncthreads();
    if (t < kNS) {
        int n = t / kNY, l2 = t % kNY;
        float2 acc = make_float2(0.f, 0.f);
        #pragma unroll
        for (int l = 0; l < kNY; ++l) cfma(acc, Fs[l2 * kNY + l], tile[n * kNY + l]);
        out[(size_t)bm * kNS + t] = acc;
    }
}

// final inverse pass along Y: take real part, scale by 1/7644, ADD into output
__global__ __launch_bounds__(256) void k_idft_y_final(
    const float2* __restrict__ in, const float2* __restrict__ F14, float* __restrict__ outp)
{
    int bm = blockIdx.x;
    __shared__ float2 tile[kNS];
    __shared__ float2 Fs[kNY * kNY];
    int t = threadIdx.x;
    if (t < kNS) tile[t] = in[(size_t)bm * kNS + t];
    if (t < kNY * kNY) { float2 f = F14[t]; f.y = -f.y; Fs[t] = f; }
    __syncthreads();
    if (t < kNS) {
        int n = t / kNY, l2 = t % kNY;
        float2 acc = make_float2(0.f, 0.f);
        #pragma unroll
        for (int l = 0; l < kNY; ++l) cfma(acc, Fs[l2 * kNY + l], tile[n * kNY + l]);
        outp[(size_t)bm * kNS + t] += acc.x * (1.0f / 7644.0f);
    }
}

// ---------------------------------------------------------------------------
// K4: transfer function H[i,k,m,n,l] = sum_{p,q,r} wr[i,k,p,q,r] r1[m] r2[n] r3[l]
// one block per (i,k)
// ---------------------------------------------------------------------------
__global__ __launch_bounds__(256) void k_H(
    const float* __restrict__ wr_re, const float* __restrict__ wr_im,
    const float2* __restrict__ r1t, const float2* __restrict__ r2t,
    const float2* __restrict__ r3t, float2* __restrict__ H)
{
    int ik = blockIdx.x;
    __shared__ float2 wrs[kMR];
    __shared__ float2 r1s[kM * kNT];
    __shared__ float2 r2s[kM * kNX];
    __shared__ float2 r3s[kM * kNY];
    __shared__ float2 As[kM * kM * kNY];   // [p][q][l] 504
    __shared__ float2 Ss[kM * kNS];        // [p][n][l] 1176
    int t = threadIdx.x;
    for (int j = t; j < kMR; j += 256)
        wrs[j] = make_float2(wr_re[ik * kMR + j], wr_im[ik * kMR + j]);
    for (int j = t; j < kM * kNT; j += 256) r1s[j] = r1t[(size_t)ik * kM * kNT + j];
    for (int j = t; j < kM * kNX; j += 256) r2s[j] = r2t[(size_t)ik * kM * kNX + j];
    for (int j = t; j < kM * kNY; j += 256) r3s[j] = r3t[(size_t)ik * kM * kNY + j];
    __syncthreads();
    for (int j = t; j < kM * kM * kNY; j += 256) {
        int l = j % kNY; int pq = j / kNY;
        float2 acc = make_float2(0.f, 0.f);
        #pragma unroll
        for (int r = 0; r < kM; ++r) cfma(acc, wrs[pq * kM + r], r3s[r * kNY + l]);
        As[j] = acc;
    }
    __syncthreads();
    for (int j = t; j < kM * kNS; j += 256) {
        int l = j % kNY; int n = (j / kNY) % kNX; int p = j / kNS;
        float2 acc = make_float2(0.f, 0.f);
        #pragma unroll
        for (int q = 0; q < kM; ++q) cfma(acc, r2s[q * kNX + n], As[(p * kM + q) * kNY + l]);
        Ss[j] = acc;
    }
    __syncthreads();
    for (int j = t; j < kNF; j += 256) {
        int m = j / kNS; int nl = j % kNS;
        float2 acc = make_float2(0.f, 0.f);
        #pragma unroll
        for (int p = 0; p < kM; ++p) cfma(acc, r1s[p * kNT + m], Ss[p * kNS + nl]);
        H[(size_t)ik * kNF + j] = acc;
    }
}

// ---------------------------------------------------------------------------
// K5: or1[b,k,f] = sum_i alpha[b,i,f] * H[i,k,f]
// ---------------------------------------------------------------------------
__global__ __launch_bounds__(256) void k_or1(
    const float2* __restrict__ alpha, const float2* __restrict__ H, float2* __restrict__ out)
{
    int id = blockIdx.x * blockDim.x + threadIdx.x;
    if (id >= kB * kC * kNF) return;
    int f = id % kNF;
    int bk = id / kNF;
    int b = bk / kC, k = bk % kC;
    float2 acc = make_float2(0.f, 0.f);
    #pragma unroll
    for (int i = 0; i < kC; ++i) {
        float2 a = alpha[(size_t)(b * kC + i) * kNF + f];
        float2 h = H[(size_t)(i * kC + k) * kNF + f];
        cfma(acc, a, h);
    }
    out[id] = acc;
}

// ---------------------------------------------------------------------------
// K7: or2[b,k,p,q,r] = -sum_i wr[i,k,p,q,r] * sum_{m,n,l} alpha[b,i,m,n,l] r1 r2 r3
// one block per (b,k); alpha contracted axis-by-axis (m -> n -> l)
// ---------------------------------------------------------------------------
__global__ __launch_bounds__(256) void k_or2(
    const float2* __restrict__ alpha,
    const float* __restrict__ wr_re, const float* __restrict__ wr_im,
    const float2* __restrict__ r1t, const float2* __restrict__ r2t,
    const float2* __restrict__ r3t, float2* __restrict__ or2)
{
    int bk = blockIdx.x; int b = bk / kC, k = bk % kC;
    __shared__ float2 r1s[kM * kNT];
    __shared__ float2 r2s[kM * kNX];
    __shared__ float2 r3s[kM * kNY];
    __shared__ float2 wrs[kMR];
    __shared__ float2 T1[kM * kNS];        // [p][n*14+l]
    __shared__ float2 T2[kM * kM * kNY];   // [p][q][l]
    __shared__ float2 acc[kMR];
    int t = threadIdx.x;
    if (t < kMR) acc[t] = make_float2(0.f, 0.f);

    for (int i = 0; i < kC; ++i) {
        __syncthreads();  // protect previous iteration's readers
        int ik = i * kC + k;
        for (int j = t; j < kM * kNT; j += 256) r1s[j] = r1t[(size_t)ik * kM * kNT + j];
        for (int j = t; j < kM * kNX; j += 256) r2s[j] = r2t[(size_t)ik * kM * kNX + j];
        for (int j = t; j < kM * kNY; j += 256) r3s[j] = r3t[(size_t)ik * kM * kNY + j];
        for (int j = t; j < kMR; j += 256)
            wrs[j] = make_float2(wr_re[ik * kMR + j], wr_im[ik * kMR + j]);
        __syncthreads();
        if (t < kNS) {
            float2 c0 = make_float2(0.f, 0.f), c1 = c0, c2 = c0, c3 = c0, c4 = c0, c5 = c0;
            const float2* ap = alpha + (size_t)(b * kC + i) * kNF + t;
            for (int m = 0; m < kNT; ++m) {
                float2 a = ap[(size_t)m * kNS];
                cfma(c0, a, r1s[0 * kNT + m]);
                cfma(c1, a, r1s[1 * kNT + m]);
                cfma(c2, a, r1s[2 * kNT + m]);
                cfma(c3, a, r1s[3 * kNT + m]);
                cfma(c4, a, r1s[4 * kNT + m]);
                cfma(c5, a, r1s[5 * kNT + m]);
            }
            T1[0 * kNS + t] = c0; T1[1 * kNS + t] = c1; T1[2 * kNS + t] = c2;
            T1[3 * kNS + t] = c3; T1[4 * kNS + t] = c4; T1[5 * kNS + t] = c5;
        }
        __syncthreads();
        for (int j = t; j < kM * kM * kNY; j += 256) {
            int l = j % kNY; int q = (j / kNY) % kM; int p = j / (kNY * kM);
            float2 a2 = make_float2(0.f, 0.f);
            #pragma unroll
            for (int n = 0; n < kNX; ++n) cfma(a2, T1[p * kNS + n * kNY + l], r2s[q * kNX + n]);
            T2[j] = a2;
        }
        __syncthreads();
        if (t < kMR) {
            int r = t % kM; int q = (t / kM) % kM; int p = t / (kM * kM);
            float2 t3 = make_float2(0.f, 0.f);
            #pragma unroll
            for (int l = 0; l < kNY; ++l) cfma(t3, T2[(p * kM + q) * kNY + l], r3s[r * kNY + l]);
            cfma(acc[t], wrs[t], t3);
        }
    }
    __syncthreads();
    if (t < kMR) {
        float2 v = acc[t];
        or2[(size_t)bk * kMR + t] = make_float2(-v.x, -v.y);
    }
}

// ---------------------------------------------------------------------------
// K8: x2[b,k,z,x,y] = (1/7644) Re( sum_{c,p,q,m} or2[b,c,p,q,m] e1[c,k,p,z] e2[c,k,q,x] e3[c,k,m,y] )
// one block per (b,k); OVERWRITES d_out (clears poison)
// ---------------------------------------------------------------------------
__global__ __launch_bounds__(256) void k_x2(
    const float2* __restrict__ or2,
    const float2* __restrict__ e1t, const float2* __restrict__ e2t,
    const float2* __restrict__ e3t, float* __restrict__ outp)
{
    int bk = blockIdx.x; int b = bk / kC, k = bk % kC;
    __shared__ float2 e1s[kM * kNT];
    __shared__ float2 e2s[kM * kNX];
    __shared__ float2 e3s[kM * kNY];
    __shared__ float2 o2s[kMR];
    __shared__ float2 Us[kM * kM * kNY];   // [p][q][y]
    int t = threadIdx.x;
    int xx = t / kNY, yy = t % kNY;
    float accz[kNT];
    #pragma unroll
    for (int z = 0; z < kNT; ++z) accz[z] = 0.f;

    for (int c = 0; c < kC; ++c) {
        __syncthreads();
        int ck = c * kC + k;
        for (int j = t; j < kM * kNT; j += 256) e1s[j] = e1t[(size_t)ck * kM * kNT + j];
        for (int j = t; j < kM * kNX; j += 256) e2s[j] = e2t[(size_t)ck * kM * kNX + j];
        for (int j = t; j < kM * kNY; j += 256) e3s[j] = e3t[(size_t)ck * kM * kNY + j];
        for (int j = t; j < kMR; j += 256) o2s[j] = or2[(size_t)(b * kC + c) * kMR + j];
        __syncthreads();
        for (int j = t; j < kM * kM * kNY; j += 256) {
            int y = j % kNY; int pq = j / kNY;
            float2 u = make_float2(0.f, 0.f);
            #pragma unroll
            for (int m = 0; m < kM; ++m) cfma(u, o2s[pq * kM + m], e3s[m * kNY + y]);
            Us[j] = u;
        }
        __syncthreads();
        if (t < kNS) {
            float2 V[kM];
            #pragma unroll
            for (int p = 0; p < kM; ++p) {
                float2 v = make_float2(0.f, 0.f);
                #pragma unroll
                for (int q = 0; q < kM; ++q) cfma(v, Us[(p * kM + q) * kNY + yy], e2s[q * kNX + xx]);
                V[p] = v;
            }
            #pragma unroll
            for (int p = 0; p < kM; ++p) {
                #pragma unroll
                for (int z = 0; z < kNT; ++z) {
                    float2 e = e1s[p * kNT + z];
                    accz[z] = fmaf(V[p].x, e.x, accz[z]);
                    accz[z] = fmaf(-V[p].y, e.y, accz[z]);
                }
            }
        }
    }
    if (t < kNS) {
        const float sc = 1.0f / 7644.0f;
        size_t base = (size_t)bk * kNF + t;
        #pragma unroll
        for (int z = 0; z < kNT; ++z) outp[base + (size_t)z * kNS] = accz[z] * sc;
    }
}

// ---------------------------------------------------------------------------
extern "C" void kernel_launch(void* const* d_in, const int* in_sizes, int n_in,
                              void* d_out, int out_size, void* d_ws, size_t ws_size,
                              hipStream_t stream) {
    (void)in_sizes; (void)n_in; (void)out_size; (void)ws_size;
    const float* x      = (const float*)d_in[0];
    const float* wp1_re = (const float*)d_in[1];
    const float* wp1_im = (const float*)d_in[2];
    const float* wp2_re = (const float*)d_in[3];
    const float* wp2_im = (const float*)d_in[4];
    const float* wp3_re = (const float*)d_in[5];
    const float* wp3_im = (const float*)d_in[6];
    const float* wr_re  = (const float*)d_in[7];
    const float* wr_im  = (const float*)d_in[8];
    float* out = (float*)d_out;

    const size_t big = (size_t)kNIK * kNF;  // 1,956,864 complex
    float2* A   = (float2*)d_ws;            // alpha
    float2* Bb  = A + big;                  // scratch / or1
    float2* Cc  = Bb + big;                 // H / ifft scratch
    float2* OR2 = Cc + big;                 // 55,296
    float2* r1t = OR2 + (size_t)kB * kC * kMR;
    float2* r2t = r1t + (size_t)kNIK * kM * kNT;
    float2* r3t = r2t + (size_t)kNIK * kM * kNX;
    float2* e1t = r3t + (size_t)kNIK * kM * kNY;
    float2* e2t = e1t + (size_t)kNIK * kM * kNT;
    float2* e3t = e2t + (size_t)kNIK * kM * kNX;
    float2* F39 = e3t + (size_t)kNIK * kM * kNY;
    float2* F14 = F39 + kNT * kNT;

    k_init<<<64, 256, 0, stream>>>(wp1_re, wp1_im, wp2_re, wp2_im, wp3_re, wp3_im,
                                   F39, F14, r1t, r2t, r3t, e1t, e2t, e3t);
    // forward FFT (DFT matmuls): x -> A -> Bb -> A   (alpha ends in A)
    k_dft_t_real<<<dim3(kNIK, kNT), 256, 0, stream>>>(x, F39, A);
    k_dft_x<<<kNIK * kNT, 256, 0, stream>>>(A, F14, Bb, 0);
    k_dft_y<<<kNIK * kNT, 256, 0, stream>>>(Bb, F14, A, 0);
    // transfer function H -> Cc
    k_H<<<kNIK, 256, 0, stream>>>(wr_re, wr_im, r1t, r2t, r3t, Cc);
    // or1 -> Bb
    k_or1<<<(kB * kC * kNF) / 256, 256, 0, stream>>>(A, Cc, Bb);
    // or2 -> OR2
    k_or2<<<kB * kC, 256, 0, stream>>>(A, wr_re, wr_im, r1t, r2t, r3t, OR2);
    // x2 -> d_out (overwrite)
    k_x2<<<kB * kC, 256, 0, stream>>>(OR2, e1t, e2t, e3t, out);
    // inverse FFT of or1: Bb -> Cc -> Bb -> (+= d_out)
    k_dft_t_cplx<<<dim3(kNIK, kNT), 256, 0, stream>>>(Bb, F39, Cc, 1);
    k_dft_x<<<kNIK * kNT, 256, 0, stream>>>(Cc, F14, Bb, 1);
    k_idft_y_final<<<kNIK * kNT, 256, 0, stream>>>(Bb, F14, out);
}

// Round 2
// 269.224 us; speedup vs baseline: 1.3087x; 1.3087x over previous
//
#include <hip/hip_runtime.h>

// Problem constants
constexpr int kB  = 16;    // batch
constexpr int kC  = 16;    // CI == CO
constexpr int kM  = 6;     // M1 == M2 == M3
constexpr int kNT = 39;
constexpr int kNX = 14;    // NXr
constexpr int kNY = 14;    // NYr
constexpr int kNS = kNX * kNY;       // 196
constexpr int kNF = kNT * kNS;       // 7644
constexpr int kNIK = kC * kC;        // 256
constexpr int kMR = kM * kM * kM;    // 216

__device__ __forceinline__ float2 cmul(float2 a, float2 b) {
    return make_float2(a.x * b.x - a.y * b.y, a.x * b.y + a.y * b.x);
}
__device__ __forceinline__ void cfma(float2& c, float2 a, float2 b) {
    c.x = fmaf(a.x, b.x, fmaf(-a.y, b.y, c.x));
    c.y = fmaf(a.x, b.y, fmaf(a.y, b.x, c.y));
}

// ---------------------------------------------------------------------------
// K0: DFT matrices + pole-reciprocal tables r1/r2/r3 + exp tables e1/e2/e3
// ---------------------------------------------------------------------------
__global__ __launch_bounds__(256) void k_init(
    const float* __restrict__ wp1_re, const float* __restrict__ wp1_im,
    const float* __restrict__ wp2_re, const float* __restrict__ wp2_im,
    const float* __restrict__ wp3_re, const float* __restrict__ wp3_im,
    float2* __restrict__ F39, float2* __restrict__ F14,
    float2* __restrict__ r1t, float2* __restrict__ r2t, float2* __restrict__ r3t,
    float2* __restrict__ e1t, float2* __restrict__ e2t, float2* __restrict__ e3t)
{
    const float PI2 = 6.283185307179586f;
    int tid = blockIdx.x * blockDim.x + threadIdx.x;
    int nth = gridDim.x * blockDim.x;

    for (int idx = tid; idx < kNT * kNT; idx += nth) {
        int m = idx / kNT, t = idx % kNT;
        float ang = -PI2 * (float)((m * t) % kNT) / (float)kNT;
        float s, c; sincosf(ang, &s, &c);
        F39[idx] = make_float2(c, s);
    }
    for (int idx = tid; idx < kNX * kNX; idx += nth) {
        int a = idx / kNX, b = idx % kNX;
        float ang = -PI2 * (float)((a * b) % kNX) / (float)kNX;
        float s, c; sincosf(ang, &s, &c);
        F14[idx] = make_float2(c, s);
    }
    for (int idx = tid; idx < kNIK * kM * kNT; idx += nth) {
        int z = idx % kNT; int ikp = idx / kNT;
        float wre = wp1_re[ikp], wim = wp1_im[ikp];
        float f = (z < 20 ? (float)z : (float)(z - kNT)) / (float)kNT;
        float w = PI2 * f;
        float dr = -wre, di = w - wim;
        float inv = 1.0f / (dr * dr + di * di);
        r1t[idx] = make_float2(dr * inv, -di * inv);
        float tt = (float)z;
        float er = expf(wre * tt);
        float s, c; sincosf(wim * tt, &s, &c);
        e1t[idx] = make_float2(er * c, er * s);
    }
    for (int idx = tid; idx < kNIK * kM * kNX; idx += nth) {
        int n = idx % kNX; int ikq = idx / kNX;
        float f = (n <= 6 ? (float)n : (float)(n - kNX)) * 27.0f / 14.0f;
        float w = PI2 * f;
        float tx = (float)n * (1.0f / 27.0f);
        {
            float wre = wp2_re[ikq], wim = wp2_im[ikq];
            float dr = -wre, di = w - wim;
            float inv = 1.0f / (dr * dr + di * di);
            r2t[idx] = make_float2(dr * inv, -di * inv);
            float er = expf(wre * tx);
            float s, c; sincosf(wim * tx, &s, &c);
            e2t[idx] = make_float2(er * c, er * s);
        }
        {
            float wre = wp3_re[ikq], wim = wp3_im[ikq];
            float dr = -wre, di = w - wim;
            float inv = 1.0f / (dr * dr + di * di);
            r3t[idx] = make_float2(dr * inv, -di * inv);
            float er = expf(wre * tx);
            float s, c; sincosf(wim * tx, &s, &c);
            e3t[idx] = make_float2(er * c, er * s);
        }
    }
}

// ---------------------------------------------------------------------------
// Forward t-DFT of real x: grid (bc, 3). Block loads the full real slab once
// into LDS and produces 13 of the 39 m-rows.
// ---------------------------------------------------------------------------
__global__ __launch_bounds__(256) void k_dft_t_real(
    const float* __restrict__ x, const float2* __restrict__ F39, float2* __restrict__ out)
{
    int bc = blockIdx.x, mg = blockIdx.y;
    __shared__ float xs[kNF];            // 30.5 KB
    __shared__ float2 Fs[13 * kNT];      // 4 KB
    int t = threadIdx.x;
    for (int j = t; j < kNF; j += 256) xs[j] = x[(size_t)bc * kNF + j];
    for (int j = t; j < 13 * kNT; j += 256)
        Fs[j] = F39[(mg * 13 + j / kNT) * kNT + (j % kNT)];
    __syncthreads();
    if (t < kNS) {
        for (int mi = 0; mi < 13; ++mi) {
            float2 acc = make_float2(0.f, 0.f);
            #pragma unroll
            for (int tt = 0; tt < kNT; ++tt) {
                float v = xs[tt * kNS + t];
                float2 f = Fs[mi * kNT + tt];
                acc.x = fmaf(f.x, v, acc.x);
                acc.y = fmaf(f.y, v, acc.y);
            }
            out[((size_t)bc * kNT + mg * 13 + mi) * kNS + t] = acc;
        }
    }
}

// ---------------------------------------------------------------------------
// Inverse t-DFT (conj F): grid (bk, 2). Block loads complex slab once,
// produces 20/19 z-rows.
// ---------------------------------------------------------------------------
__global__ __launch_bounds__(256) void k_idft_t(
    const float2* __restrict__ in, const float2* __restrict__ F39, float2* __restrict__ out)
{
    int bk = blockIdx.x, zg = blockIdx.y;
    int z0 = zg ? 20 : 0;
    int nz = zg ? 19 : 20;
    __shared__ float2 slab[kNF];         // 61 KB
    __shared__ float2 Fs[20 * kNT];      // 6.2 KB
    int t = threadIdx.x;
    for (int j = t; j < kNF; j += 256) slab[j] = in[(size_t)bk * kNF + j];
    for (int j = t; j < nz * kNT; j += 256) {
        float2 f = F39[(z0 + j / kNT) * kNT + (j % kNT)];
        f.y = -f.y;
        Fs[j] = f;
    }
    __syncthreads();
    if (t < kNS) {
        for (int zi = 0; zi < nz; ++zi) {
            float2 acc = make_float2(0.f, 0.f);
            #pragma unroll
            for (int m = 0; m < kNT; ++m) cfma(acc, Fs[zi * kNT + m], slab[m * kNS + t]);
            out[((size_t)bk * kNT + z0 + zi) * kNS + t] = acc;
        }
    }
}

// ---------------------------------------------------------------------------
// Fused forward x+y DFT on one 14x14 tile. Block per (bc*39+m).
// ---------------------------------------------------------------------------
__global__ __launch_bounds__(256) void k_dft_xy(
    const float2* __restrict__ in, const float2* __restrict__ F14, float2* __restrict__ out)
{
    int bm = blockIdx.x;
    __shared__ float2 tile[kNS];
    __shared__ float2 tmp[kNS];
    __shared__ float2 Fs[kNX * kNX];
    int t = threadIdx.x;
    if (t < kNS) tile[t] = in[(size_t)bm * kNS + t];
    if (t < kNX * kNX) Fs[t] = F14[t];
    __syncthreads();
    if (t < kNS) {
        int n2 = t / kNY, l = t % kNY;
        float2 acc = make_float2(0.f, 0.f);
        #pragma unroll
        for (int n = 0; n < kNX; ++n) cfma(acc, Fs[n2 * kNX + n], tile[n * kNY + l]);
        tmp[t] = acc;
    }
    __syncthreads();
    if (t < kNS) {
        int n = t / kNY, l2 = t % kNY;
        float2 acc = make_float2(0.f, 0.f);
        #pragma unroll
        for (int l = 0; l < kNY; ++l) cfma(acc, Fs[l2 * kNY + l], tmp[n * kNY + l]);
        out[(size_t)bm * kNS + t] = acc;
    }
}

// Fused inverse x+y DFT + take-real + scale + add into output.
__global__ __launch_bounds__(256) void k_idft_xy_final(
    const float2* __restrict__ in, const float2* __restrict__ F14, float* __restrict__ outp)
{
    int bm = blockIdx.x;
    __shared__ float2 tile[kNS];
    __shared__ float2 tmp[kNS];
    __shared__ float2 Fs[kNX * kNX];
    int t = threadIdx.x;
    if (t < kNS) tile[t] = in[(size_t)bm * kNS + t];
    if (t < kNX * kNX) { float2 f = F14[t]; f.y = -f.y; Fs[t] = f; }
    __syncthreads();
    if (t < kNS) {
        int n2 = t / kNY, l = t % kNY;
        float2 acc = make_float2(0.f, 0.f);
        #pragma unroll
        for (int n = 0; n < kNX; ++n) cfma(acc, Fs[n2 * kNX + n], tile[n * kNY + l]);
        tmp[t] = acc;
    }
    __syncthreads();
    if (t < kNS) {
        int n = t / kNY, l2 = t % kNY;
        float2 acc = make_float2(0.f, 0.f);
        #pragma unroll
        for (int l = 0; l < kNY; ++l) cfma(acc, Fs[l2 * kNY + l], tmp[n * kNY + l]);
        outp[(size_t)bm * kNS + t] += acc.x * (1.0f / 7644.0f);
    }
}

// ---------------------------------------------------------------------------
// K4: H[i,k,m,n,l] = sum_{p,q,r} wr[i,k,p,q,r] r1[m] r2[n] r3[l]; block per (i,k)
// ---------------------------------------------------------------------------
__global__ __launch_bounds__(256) void k_H(
    const float* __restrict__ wr_re, const float* __restrict__ wr_im,
    const float2* __restrict__ r1t, const float2* __restrict__ r2t,
    const float2* __restrict__ r3t, float2* __restrict__ H)
{
    int ik = blockIdx.x;
    __shared__ float2 wrs[kMR];
    __shared__ float2 r1s[kM * kNT];
    __shared__ float2 r2s[kM * kNX];
    __shared__ float2 r3s[kM * kNY];
    __shared__ float2 As[kM * kM * kNY];
    __shared__ float2 Ss[kM * kNS];
    int t = threadIdx.x;
    for (int j = t; j < kMR; j += 256)
        wrs[j] = make_float2(wr_re[ik * kMR + j], wr_im[ik * kMR + j]);
    for (int j = t; j < kM * kNT; j += 256) r1s[j] = r1t[(size_t)ik * kM * kNT + j];
    for (int j = t; j < kM * kNX; j += 256) r2s[j] = r2t[(size_t)ik * kM * kNX + j];
    for (int j = t; j < kM * kNY; j += 256) r3s[j] = r3t[(size_t)ik * kM * kNY + j];
    __syncthreads();
    for (int j = t; j < kM * kM * kNY; j += 256) {
        int l = j % kNY; int pq = j / kNY;
        float2 acc = make_float2(0.f, 0.f);
        #pragma unroll
        for (int r = 0; r < kM; ++r) cfma(acc, wrs[pq * kM + r], r3s[r * kNY + l]);
        As[j] = acc;
    }
    __syncthreads();
    for (int j = t; j < kM * kNS; j += 256) {
        int l = j % kNY; int n = (j / kNY) % kNX; int p = j / kNS;
        float2 acc = make_float2(0.f, 0.f);
        #pragma unroll
        for (int q = 0; q < kM; ++q) cfma(acc, r2s[q * kNX + n], As[(p * kM + q) * kNY + l]);
        Ss[j] = acc;
    }
    __syncthreads();
    for (int j = t; j < kNF; j += 256) {
        int m = j / kNS; int nl = j % kNS;
        float2 acc = make_float2(0.f, 0.f);
        #pragma unroll
        for (int p = 0; p < kM; ++p) cfma(acc, r1s[p * kNT + m], Ss[p * kNS + nl]);
        H[(size_t)ik * kNF + j] = acc;
    }
}

// ---------------------------------------------------------------------------
// K5: or1[b,k,f] = sum_i alpha[b,i,f] * H[i,k,f]
// ---------------------------------------------------------------------------
__global__ __launch_bounds__(256) void k_or1(
    const float2* __restrict__ alpha, const float2* __restrict__ H, float2* __restrict__ out)
{
    int id = blockIdx.x * blockDim.x + threadIdx.x;
    if (id >= kB * kC * kNF) return;
    int f = id % kNF;
    int bk = id / kNF;
    int b = bk / kC, k = bk % kC;
    float2 acc = make_float2(0.f, 0.f);
    #pragma unroll
    for (int i = 0; i < kC; ++i) {
        float2 a = alpha[(size_t)(b * kC + i) * kNF + f];
        float2 h = H[(size_t)(i * kC + k) * kNF + f];
        cfma(acc, a, h);
    }
    out[id] = acc;
}

// ---------------------------------------------------------------------------
// K7a: partial or2 per (b,k,i): P[(bk*16+i)*216+t] = wr[ik,t] * G[b,i,k,t]
// where G = sum_{m,n,l} alpha[b,i,m,n,l] r1 r2 r3. One block per (b,k,i).
// ---------------------------------------------------------------------------
__global__ __launch_bounds__(256) void k_or2p(
    const float2* __restrict__ alpha,
    const float* __restrict__ wr_re, const float* __restrict__ wr_im,
    const float2* __restrict__ r1t, const float2* __restrict__ r2t,
    const float2* __restrict__ r3t, float2* __restrict__ P)
{
    int blk = blockIdx.x;            // bk*16 + i
    int i = blk % kC; int bk = blk / kC;
    int b = bk / kC, k = bk % kC;
    int ik = i * kC + k;
    __shared__ float2 r1s[kM * kNT];
    __shared__ float2 r2s[kM * kNX];
    __shared__ float2 r3s[kM * kNY];
    __shared__ float2 wrs[kMR];
    __shared__ float2 T1[kM * kNS];
    __shared__ float2 T2[kM * kM * kNY];
    int t = threadIdx.x;
    for (int j = t; j < kM * kNT; j += 256) r1s[j] = r1t[(size_t)ik * kM * kNT + j];
    for (int j = t; j < kM * kNX; j += 256) r2s[j] = r2t[(size_t)ik * kM * kNX + j];
    for (int j = t; j < kM * kNY; j += 256) r3s[j] = r3t[(size_t)ik * kM * kNY + j];
    for (int j = t; j < kMR; j += 256)
        wrs[j] = make_float2(wr_re[ik * kMR + j], wr_im[ik * kMR + j]);
    __syncthreads();
    if (t < kNS) {
        float2 c0 = make_float2(0.f, 0.f), c1 = c0, c2 = c0, c3 = c0, c4 = c0, c5 = c0;
        const float2* ap = alpha + (size_t)(b * kC + i) * kNF + t;
        for (int m = 0; m < kNT; ++m) {
            float2 a = ap[(size_t)m * kNS];
            cfma(c0, a, r1s[0 * kNT + m]);
            cfma(c1, a, r1s[1 * kNT + m]);
            cfma(c2, a, r1s[2 * kNT + m]);
            cfma(c3, a, r1s[3 * kNT + m]);
            cfma(c4, a, r1s[4 * kNT + m]);
            cfma(c5, a, r1s[5 * kNT + m]);
        }
        T1[0 * kNS + t] = c0; T1[1 * kNS + t] = c1; T1[2 * kNS + t] = c2;
        T1[3 * kNS + t] = c3; T1[4 * kNS + t] = c4; T1[5 * kNS + t] = c5;
    }
    __syncthreads();
    for (int j = t; j < kM * kM * kNY; j += 256) {
        int l = j % kNY; int q = (j / kNY) % kM; int p = j / (kNY * kM);
        float2 a2 = make_float2(0.f, 0.f);
        #pragma unroll
        for (int n = 0; n < kNX; ++n) cfma(a2, T1[p * kNS + n * kNY + l], r2s[q * kNX + n]);
        T2[j] = a2;
    }
    __syncthreads();
    if (t < kMR) {
        int r = t % kM; int q = (t / kM) % kM; int p = t / (kM * kM);
        float2 t3 = make_float2(0.f, 0.f);
        #pragma unroll
        for (int l = 0; l < kNY; ++l) cfma(t3, T2[(p * kM + q) * kNY + l], r3s[r * kNY + l]);
        P[(size_t)blk * kMR + t] = cmul(wrs[t], t3);
    }
}

// K7b: or2[bk][t] = -sum_i P[(bk*16+i)*216+t]
__global__ __launch_bounds__(256) void k_or2red(
    const float2* __restrict__ P, float2* __restrict__ or2)
{
    int id = blockIdx.x * blockDim.x + threadIdx.x;
    if (id >= kB * kC * kMR) return;
    int t = id % kMR; int bk = id / kMR;
    float2 s = make_float2(0.f, 0.f);
    #pragma unroll
    for (int i = 0; i < kC; ++i) {
        float2 v = P[((size_t)bk * kC + i) * kMR + t];
        s.x += v.x; s.y += v.y;
    }
    or2[id] = make_float2(-s.x, -s.y);
}

// ---------------------------------------------------------------------------
// K8: x2, split z across 3 blocks per (b,k). grid (256, 3).
// ---------------------------------------------------------------------------
__global__ __launch_bounds__(256) void k_x2z(
    const float2* __restrict__ or2,
    const float2* __restrict__ e1t, const float2* __restrict__ e2t,
    const float2* __restrict__ e3t, float* __restrict__ outp)
{
    int bk = blockIdx.x; int b = bk / kC, k = bk % kC;
    int z0 = blockIdx.y * 13;
    __shared__ float2 e1s[kM * kNT];
    __shared__ float2 e2s[kM * kNX];
    __shared__ float2 e3s[kM * kNY];
    __shared__ float2 o2s[kMR];
    __shared__ float2 Us[kM * kM * kNY];
    int t = threadIdx.x;
    int xx = t / kNY, yy = t % kNY;
    float accz[13];
    #pragma unroll
    for (int zi = 0; zi < 13; ++zi) accz[zi] = 0.f;

    for (int c = 0; c < kC; ++c) {
        __syncthreads();
        int ck = c * kC + k;
        for (int j = t; j < kM * kNT; j += 256) e1s[j] = e1t[(size_t)ck * kM * kNT + j];
        for (int j = t; j < kM * kNX; j += 256) e2s[j] = e2t[(size_t)ck * kM * kNX + j];
        for (int j = t; j < kM * kNY; j += 256) e3s[j] = e3t[(size_t)ck * kM * kNY + j];
        for (int j = t; j < kMR; j += 256) o2s[j] = or2[(size_t)(b * kC + c) * kMR + j];
        __syncthreads();
        for (int j = t; j < kM * kM * kNY; j += 256) {
            int y = j % kNY; int pq = j / kNY;
            float2 u = make_float2(0.f, 0.f);
            #pragma unroll
            for (int m = 0; m < kM; ++m) cfma(u, o2s[pq * kM + m], e3s[m * kNY + y]);
            Us[j] = u;
        }
        __syncthreads();
        if (t < kNS) {
            float2 V[kM];
            #pragma unroll
            for (int p = 0; p < kM; ++p) {
                float2 v = make_float2(0.f, 0.f);
                #pragma unroll
                for (int q = 0; q < kM; ++q) cfma(v, Us[(p * kM + q) * kNY + yy], e2s[q * kNX + xx]);
                V[p] = v;
            }
            #pragma unroll
            for (int p = 0; p < kM; ++p) {
                #pragma unroll
                for (int zi = 0; zi < 13; ++zi) {
                    float2 e = e1s[p * kNT + z0 + zi];
                    accz[zi] = fmaf(V[p].x, e.x, accz[zi]);
                    accz[zi] = fmaf(-V[p].y, e.y, accz[zi]);
                }
            }
        }
    }
    if (t < kNS) {
        const float sc = 1.0f / 7644.0f;
        size_t base = (size_t)bk * kNF + (size_t)z0 * kNS + t;
        #pragma unroll
        for (int zi = 0; zi < 13; ++zi) outp[base + (size_t)zi * kNS] = accz[zi] * sc;
    }
}

// ---------------------------------------------------------------------------
extern "C" void kernel_launch(void* const* d_in, const int* in_sizes, int n_in,
                              void* d_out, int out_size, void* d_ws, size_t ws_size,
                              hipStream_t stream) {
    (void)in_sizes; (void)n_in; (void)out_size; (void)ws_size;
    const float* x      = (const float*)d_in[0];
    const float* wp1_re = (const float*)d_in[1];
    const float* wp1_im = (const float*)d_in[2];
    const float* wp2_re = (const float*)d_in[3];
    const float* wp2_im = (const float*)d_in[4];
    const float* wp3_re = (const float*)d_in[5];
    const float* wp3_im = (const float*)d_in[6];
    const float* wr_re  = (const float*)d_in[7];
    const float* wr_im  = (const float*)d_in[8];
    float* out = (float*)d_out;

    const size_t big = (size_t)kNIK * kNF;  // 1,956,864 complex
    float2* A   = (float2*)d_ws;            // scratch 1
    float2* Bb  = A + big;                  // scratch 2 (alpha)
    float2* Cc  = Bb + big;                 // H, then or2 partials, then ifft scratch
    float2* OR2 = Cc + big;                 // 55,296
    float2* r1t = OR2 + (size_t)kB * kC * kMR;
    float2* r2t = r1t + (size_t)kNIK * kM * kNT;
    float2* r3t = r2t + (size_t)kNIK * kM * kNX;
    float2* e1t = r3t + (size_t)kNIK * kM * kNY;
    float2* e2t = e1t + (size_t)kNIK * kM * kNT;
    float2* e3t = e2t + (size_t)kNIK * kM * kNX;
    float2* F39 = e3t + (size_t)kNIK * kM * kNY;
    float2* F14 = F39 + kNT * kNT;

    k_init<<<64, 256, 0, stream>>>(wp1_re, wp1_im, wp2_re, wp2_im, wp3_re, wp3_im,
                                   F39, F14, r1t, r2t, r3t, e1t, e2t, e3t);
    // forward DFT: x -> A (t-pass) -> Bb (fused xy). alpha lives in Bb.
    k_dft_t_real<<<dim3(kNIK, 3), 256, 0, stream>>>(x, F39, A);
    k_dft_xy<<<kNIK * kNT, 256, 0, stream>>>(A, F14, Bb);
    // transfer function H -> Cc; or1 -> A
    k_H<<<kNIK, 256, 0, stream>>>(wr_re, wr_im, r1t, r2t, r3t, Cc);
    k_or1<<<(kB * kC * kNF) / 256, 256, 0, stream>>>(Bb, Cc, A);
    // or2: partials into Cc (H no longer needed), then reduce -> OR2
    k_or2p<<<kB * kC * kC, 256, 0, stream>>>(Bb, wr_re, wr_im, r1t, r2t, r3t, Cc);
    k_or2red<<<(kB * kC * kMR + 255) / 256, 256, 0, stream>>>(Cc, OR2);
    // x2 -> d_out (overwrite, all 39 z covered by 3 z-chunks)
    k_x2z<<<dim3(kB * kC, 3), 256, 0, stream>>>(OR2, e1t, e2t, e3t, out);
    // inverse FFT of or1 (in A): A -> Cc (t-pass) -> += d_out (fused xy + add)
    k_idft_t<<<dim3(kB * kC, 2), 256, 0, stream>>>(A, F39, Cc);
    k_idft_xy_final<<<kNIK * kNT, 256, 0, stream>>>(Cc, F14, out);
}

// Round 4
// 225.040 us; speedup vs baseline: 1.5656x; 1.1963x over previous
//
#include <hip/hip_runtime.h>

// Problem constants
constexpr int kB  = 16;    // batch
constexpr int kC  = 16;    // CI == CO
constexpr int kM  = 6;     // M1 == M2 == M3
constexpr int kNT = 39;
constexpr int kNX = 14;    // NXr
constexpr int kNY = 14;    // NYr
constexpr int kNS = kNX * kNY;       // 196
constexpr int kNF = kNT * kNS;       // 7644
constexpr int kNIK = kC * kC;        // 256
constexpr int kMR = kM * kM * kM;    // 216
constexpr int kFCH = 6;              // f-chunk for k_or1 (7644 = 6*1274)

__device__ __forceinline__ float2 cmul(float2 a, float2 b) {
    return make_float2(a.x * b.x - a.y * b.y, a.x * b.y + a.y * b.x);
}
__device__ __forceinline__ void cfma(float2& c, float2 a, float2 b) {
    c.x = fmaf(a.x, b.x, fmaf(-a.y, b.y, c.x));
    c.y = fmaf(a.x, b.y, fmaf(a.y, b.x, c.y));
}

// ---------------------------------------------------------------------------
// K0: DFT matrices + pole-reciprocal tables r1/r2/r3 + exp tables e1/e2/e3
// ---------------------------------------------------------------------------
__global__ __launch_bounds__(256) void k_init(
    const float* __restrict__ wp1_re, const float* __restrict__ wp1_im,
    const float* __restrict__ wp2_re, const float* __restrict__ wp2_im,
    const float* __restrict__ wp3_re, const float* __restrict__ wp3_im,
    float2* __restrict__ F39, float2* __restrict__ F14,
    float2* __restrict__ r1t, float2* __restrict__ r2t, float2* __restrict__ r3t,
    float2* __restrict__ e1t, float2* __restrict__ e2t, float2* __restrict__ e3t)
{
    const float PI2 = 6.283185307179586f;
    int tid = blockIdx.x * blockDim.x + threadIdx.x;
    int nth = gridDim.x * blockDim.x;

    for (int idx = tid; idx < kNT * kNT; idx += nth) {
        int m = idx / kNT, t = idx % kNT;
        float ang = -PI2 * (float)((m * t) % kNT) / (float)kNT;
        float s, c; sincosf(ang, &s, &c);
        F39[idx] = make_float2(c, s);
    }
    for (int idx = tid; idx < kNX * kNX; idx += nth) {
        int a = idx / kNX, b = idx % kNX;
        float ang = -PI2 * (float)((a * b) % kNX) / (float)kNX;
        float s, c; sincosf(ang, &s, &c);
        F14[idx] = make_float2(c, s);
    }
    for (int idx = tid; idx < kNIK * kM * kNT; idx += nth) {
        int z = idx % kNT; int ikp = idx / kNT;
        float wre = wp1_re[ikp], wim = wp1_im[ikp];
        float f = (z < 20 ? (float)z : (float)(z - kNT)) / (float)kNT;
        float w = PI2 * f;
        float dr = -wre, di = w - wim;
        float inv = 1.0f / (dr * dr + di * di);
        r1t[idx] = make_float2(dr * inv, -di * inv);
        float tt = (float)z;
        float er = expf(wre * tt);
        float s, c; sincosf(wim * tt, &s, &c);
        e1t[idx] = make_float2(er * c, er * s);
    }
    for (int idx = tid; idx < kNIK * kM * kNX; idx += nth) {
        int n = idx % kNX; int ikq = idx / kNX;
        float f = (n <= 6 ? (float)n : (float)(n - kNX)) * 27.0f / 14.0f;
        float w = PI2 * f;
        float tx = (float)n * (1.0f / 27.0f);
        {
            float wre = wp2_re[ikq], wim = wp2_im[ikq];
            float dr = -wre, di = w - wim;
            float inv = 1.0f / (dr * dr + di * di);
            r2t[idx] = make_float2(dr * inv, -di * inv);
            float er = expf(wre * tx);
            float s, c; sincosf(wim * tx, &s, &c);
            e2t[idx] = make_float2(er * c, er * s);
        }
        {
            float wre = wp3_re[ikq], wim = wp3_im[ikq];
            float dr = -wre, di = w - wim;
            float inv = 1.0f / (dr * dr + di * di);
            r3t[idx] = make_float2(dr * inv, -di * inv);
            float er = expf(wre * tx);
            float s, c; sincosf(wim * tx, &s, &c);
            e3t[idx] = make_float2(er * c, er * s);
        }
    }
}

// ---------------------------------------------------------------------------
// Forward t-DFT of real x, register-column form. grid (bc, 3); thread owns s.
// ---------------------------------------------------------------------------
__global__ __launch_bounds__(256) void k_dft_t_real(
    const float* __restrict__ x, const float2* __restrict__ F39, float2* __restrict__ out)
{
    int bc = blockIdx.x, mg = blockIdx.y;
    __shared__ float2 Fs[13 * kNT];
    int t = threadIdx.x;
    for (int j = t; j < 13 * kNT; j += 256)
        Fs[j] = F39[(mg * 13 + j / kNT) * kNT + (j % kNT)];
    __syncthreads();
    if (t < kNS) {
        float col[kNT];
        const float* xp = x + (size_t)bc * kNF + t;
        #pragma unroll
        for (int tt = 0; tt < kNT; ++tt) col[tt] = xp[(size_t)tt * kNS];
        for (int mi = 0; mi < 13; ++mi) {
            float2 acc = make_float2(0.f, 0.f);
            #pragma unroll
            for (int tt = 0; tt < kNT; ++tt) {
                float2 f = Fs[mi * kNT + tt];
                acc.x = fmaf(f.x, col[tt], acc.x);
                acc.y = fmaf(f.y, col[tt], acc.y);
            }
            out[((size_t)bc * kNT + mg * 13 + mi) * kNS + t] = acc;
        }
    }
}

// ---------------------------------------------------------------------------
// Inverse t-DFT (conj F), register-column form. grid (bk, 3); thread owns s.
// ---------------------------------------------------------------------------
__global__ __launch_bounds__(256) void k_idft_t(
    const float2* __restrict__ in, const float2* __restrict__ F39, float2* __restrict__ out)
{
    int bk = blockIdx.x, zg = blockIdx.y;
    __shared__ float2 Fs[13 * kNT];
    int t = threadIdx.x;
    for (int j = t; j < 13 * kNT; j += 256) {
        float2 f = F39[(zg * 13 + j / kNT) * kNT + (j % kNT)];
        f.y = -f.y;
        Fs[j] = f;
    }
    __syncthreads();
    if (t < kNS) {
        float2 col[kNT];
        const float2* ip = in + (size_t)bk * kNF + t;
        #pragma unroll
        for (int m = 0; m < kNT; ++m) col[m] = ip[(size_t)m * kNS];
        for (int zi = 0; zi < 13; ++zi) {
            float2 acc = make_float2(0.f, 0.f);
            #pragma unroll
            for (int m = 0; m < kNT; ++m) cfma(acc, Fs[zi * kNT + m], col[m]);
            out[((size_t)bk * kNT + zg * 13 + zi) * kNS + t] = acc;
        }
    }
}

// ---------------------------------------------------------------------------
// Fused forward x+y DFT on one 14x14 tile. Block per (bc*39+m).
// ---------------------------------------------------------------------------
__global__ __launch_bounds__(256) void k_dft_xy(
    const float2* __restrict__ in, const float2* __restrict__ F14, float2* __restrict__ out)
{
    int bm = blockIdx.x;
    __shared__ float2 tile[kNS];
    __shared__ float2 tmp[kNS];
    __shared__ float2 Fs[kNX * kNX];
    int t = threadIdx.x;
    if (t < kNS) tile[t] = in[(size_t)bm * kNS + t];
    if (t < kNX * kNX) Fs[t] = F14[t];
    __syncthreads();
    if (t < kNS) {
        int n2 = t / kNY, l = t % kNY;
        float2 acc = make_float2(0.f, 0.f);
        #pragma unroll
        for (int n = 0; n < kNX; ++n) cfma(acc, Fs[n2 * kNX + n], tile[n * kNY + l]);
        tmp[t] = acc;
    }
    __syncthreads();
    if (t < kNS) {
        int n = t / kNY, l2 = t % kNY;
        float2 acc = make_float2(0.f, 0.f);
        #pragma unroll
        for (int l = 0; l < kNY; ++l) cfma(acc, Fs[l2 * kNY + l], tmp[n * kNY + l]);
        out[(size_t)bm * kNS + t] = acc;
    }
}

// Fused inverse x+y DFT + take-real + scale + add into output.
__global__ __launch_bounds__(256) void k_idft_xy_final(
    const float2* __restrict__ in, const float2* __restrict__ F14, float* __restrict__ outp)
{
    int bm = blockIdx.x;
    __shared__ float2 tile[kNS];
    __shared__ float2 tmp[kNS];
    __shared__ float2 Fs[kNX * kNX];
    int t = threadIdx.x;
    if (t < kNS) tile[t] = in[(size_t)bm * kNS + t];
    if (t < kNX * kNX) { float2 f = F14[t]; f.y = -f.y; Fs[t] = f; }
    __syncthreads();
    if (t < kNS) {
        int n2 = t / kNY, l = t % kNY;
        float2 acc = make_float2(0.f, 0.f);
        #pragma unroll
        for (int n = 0; n < kNX; ++n) cfma(acc, Fs[n2 * kNX + n], tile[n * kNY + l]);
        tmp[t] = acc;
    }
    __syncthreads();
    if (t < kNS) {
        int n = t / kNY, l2 = t % kNY;
        float2 acc = make_float2(0.f, 0.f);
        #pragma unroll
        for (int l = 0; l < kNY; ++l) cfma(acc, Fs[l2 * kNY + l], tmp[n * kNY + l]);
        outp[(size_t)bm * kNS + t] += acc.x * (1.0f / 7644.0f);
    }
}

// ---------------------------------------------------------------------------
// K4: H[i,k,m,n,l] = sum_{p,q,r} wr[i,k,p,q,r] r1[m] r2[n] r3[l]; block per (i,k)
// ---------------------------------------------------------------------------
__global__ __launch_bounds__(256) void k_H(
    const float* __restrict__ wr_re, const float* __restrict__ wr_im,
    const float2* __restrict__ r1t, const float2* __restrict__ r2t,
    const float2* __restrict__ r3t, float2* __restrict__ H)
{
    int ik = blockIdx.x;
    __shared__ float2 wrs[kMR];
    __shared__ float2 r1s[kM * kNT];
    __shared__ float2 r2s[kM * kNX];
    __shared__ float2 r3s[kM * kNY];
    __shared__ float2 As[kM * kM * kNY];
    __shared__ float2 Ss[kM * kNS];
    int t = threadIdx.x;
    for (int j = t; j < kMR; j += 256)
        wrs[j] = make_float2(wr_re[ik * kMR + j], wr_im[ik * kMR + j]);
    for (int j = t; j < kM * kNT; j += 256) r1s[j] = r1t[(size_t)ik * kM * kNT + j];
    for (int j = t; j < kM * kNX; j += 256) r2s[j] = r2t[(size_t)ik * kM * kNX + j];
    for (int j = t; j < kM * kNY; j += 256) r3s[j] = r3t[(size_t)ik * kM * kNY + j];
    __syncthreads();
    for (int j = t; j < kM * kM * kNY; j += 256) {
        int l = j % kNY; int pq = j / kNY;
        float2 acc = make_float2(0.f, 0.f);
        #pragma unroll
        for (int r = 0; r < kM; ++r) cfma(acc, wrs[pq * kM + r], r3s[r * kNY + l]);
        As[j] = acc;
    }
    __syncthreads();
    for (int j = t; j < kM * kNS; j += 256) {
        int l = j % kNY; int n = (j / kNY) % kNX; int p = j / kNS;
        float2 acc = make_float2(0.f, 0.f);
        #pragma unroll
        for (int q = 0; q < kM; ++q) cfma(acc, r2s[q * kNX + n], As[(p * kM + q) * kNY + l]);
        Ss[j] = acc;
    }
    __syncthreads();
    for (int j = t; j < kNF; j += 256) {
        int m = j / kNS; int nl = j % kNS;
        float2 acc = make_float2(0.f, 0.f);
        #pragma unroll
        for (int p = 0; p < kM; ++p) cfma(acc, r1s[p * kNT + m], Ss[p * kNS + nl]);
        H[(size_t)ik * kNF + j] = acc;
    }
}

// ---------------------------------------------------------------------------
// K5: or1[b,k,f] = sum_i alpha[b,i,f] * H[i,k,f]
// f-chunked, LDS-staged (16x reuse). One block per 6 f's; thread = (b,k).
// Skewed LDS layout breaks the 16-row-stride bank aliasing.
// ---------------------------------------------------------------------------
__global__ __launch_bounds__(256) void k_or1(
    const float2* __restrict__ alpha, const float2* __restrict__ H, float2* __restrict__ out)
{
    int f0 = blockIdx.x * kFCH;
    __shared__ float2 As[256 * 7 + 16];
    __shared__ float2 Hs[256 * 7 + 16];
    int t = threadIdx.x;
    {
        const float2* ap = alpha + (size_t)t * kNF + f0;
        const float2* hp = H + (size_t)t * kNF + f0;
        int base = t * 7 + (t >> 4);
        #pragma unroll
        for (int j = 0; j < kFCH; ++j) {
            As[base + j] = ap[j];
            Hs[base + j] = hp[j];
        }
    }
    __syncthreads();
    int b = t >> 4, k = t & 15;
    float2 acc[kFCH];
    #pragma unroll
    for (int j = 0; j < kFCH; ++j) acc[j] = make_float2(0.f, 0.f);
    #pragma unroll
    for (int i = 0; i < kC; ++i) {
        int ai = (b * 16 + i) * 7 + b;
        int hi = (i * 16 + k) * 7 + i;
        #pragma unroll
        for (int j = 0; j < kFCH; ++j) cfma(acc[j], As[ai + j], Hs[hi + j]);
    }
    float2* op = out + (size_t)t * kNF + f0;
    #pragma unroll
    for (int j = 0; j < kFCH; ++j) op[j] = acc[j];
}

// ---------------------------------------------------------------------------
// K7a: partial or2 per (b,k,i): P[(bk*16+i)*216+t] = wr[ik,t] * G[b,i,k,t]
// ---------------------------------------------------------------------------
__global__ __launch_bounds__(256) void k_or2p(
    const float2* __restrict__ alpha,
    const float* __restrict__ wr_re, const float* __restrict__ wr_im,
    const float2* __restrict__ r1t, const float2* __restrict__ r2t,
    const float2* __restrict__ r3t, float2* __restrict__ P)
{
    int blk = blockIdx.x;            // bk*16 + i
    int i = blk % kC; int bk = blk / kC;
    int b = bk / kC, k = bk % kC;
    int ik = i * kC + k;
    __shared__ float2 r1s[kM * kNT];
    __shared__ float2 r2s[kM * kNX];
    __shared__ float2 r3s[kM * kNY];
    __shared__ float2 wrs[kMR];
    __shared__ float2 T1[kM * kNS];
    __shared__ float2 T2[kM * kM * kNY];
    int t = threadIdx.x;
    for (int j = t; j < kM * kNT; j += 256) r1s[j] = r1t[(size_t)ik * kM * kNT + j];
    for (int j = t; j < kM * kNX; j += 256) r2s[j] = r2t[(size_t)ik * kM * kNX + j];
    for (int j = t; j < kM * kNY; j += 256) r3s[j] = r3t[(size_t)ik * kM * kNY + j];
    for (int j = t; j < kMR; j += 256)
        wrs[j] = make_float2(wr_re[ik * kMR + j], wr_im[ik * kMR + j]);
    __syncthreads();
    if (t < kNS) {
        float2 c0 = make_float2(0.f, 0.f), c1 = c0, c2 = c0, c3 = c0, c4 = c0, c5 = c0;
        const float2* ap = alpha + (size_t)(b * kC + i) * kNF + t;
        for (int m = 0; m < kNT; ++m) {
            float2 a = ap[(size_t)m * kNS];
            cfma(c0, a, r1s[0 * kNT + m]);
            cfma(c1, a, r1s[1 * kNT + m]);
            cfma(c2, a, r1s[2 * kNT + m]);
            cfma(c3, a, r1s[3 * kNT + m]);
            cfma(c4, a, r1s[4 * kNT + m]);
            cfma(c5, a, r1s[5 * kNT + m]);
        }
        T1[0 * kNS + t] = c0; T1[1 * kNS + t] = c1; T1[2 * kNS + t] = c2;
        T1[3 * kNS + t] = c3; T1[4 * kNS + t] = c4; T1[5 * kNS + t] = c5;
    }
    __syncthreads();
    for (int j = t; j < kM * kM * kNY; j += 256) {
        int l = j % kNY; int q = (j / kNY) % kM; int p = j / (kNY * kM);
        float2 a2 = make_float2(0.f, 0.f);
        #pragma unroll
        for (int n = 0; n < kNX; ++n) cfma(a2, T1[p * kNS + n * kNY + l], r2s[q * kNX + n]);
        T2[j] = a2;
    }
    __syncthreads();
    if (t < kMR) {
        int r = t % kM; int q = (t / kM) % kM; int p = t / (kM * kM);
        float2 t3 = make_float2(0.f, 0.f);
        #pragma unroll
        for (int l = 0; l < kNY; ++l) cfma(t3, T2[(p * kM + q) * kNY + l], r3s[r * kNY + l]);
        P[(size_t)blk * kMR + t] = cmul(wrs[t], t3);
    }
}

// K7b: or2[bk][t] = -sum_i P[(bk*16+i)*216+t]
__global__ __launch_bounds__(256) void k_or2red(
    const float2* __restrict__ P, float2* __restrict__ or2)
{
    int id = blockIdx.x * blockDim.x + threadIdx.x;
    if (id >= kB * kC * kMR) return;
    int t = id % kMR; int bk = id / kMR;
    float2 s = make_float2(0.f, 0.f);
    #pragma unroll
    for (int i = 0; i < kC; ++i) {
        float2 v = P[((size_t)bk * kC + i) * kMR + t];
        s.x += v.x; s.y += v.y;
    }
    or2[id] = make_float2(-s.x, -s.y);
}

// ---------------------------------------------------------------------------
// K8a: x2 partials. grid (256, 3 zg, 2 cg); 8 c's per block; 13 z's per block.
// Writes raw partial sums (no scale) into P2[(bk*2+cg)*kNF + z*196 + t].
// ---------------------------------------------------------------------------
__global__ __launch_bounds__(256) void k_x2zp(
    const float2* __restrict__ or2,
    const float2* __restrict__ e1t, const float2* __restrict__ e2t,
    const float2* __restrict__ e3t, float* __restrict__ P2)
{
    int bk = blockIdx.x; int b = bk / kC, k = bk % kC;
    int z0 = blockIdx.y * 13;
    int c0 = blockIdx.z * 8;
    __shared__ float2 e1s[kM * kNT];
    __shared__ float2 e2s[kM * kNX];
    __shared__ float2 e3s[kM * kNY];
    __shared__ float2 o2s[kMR];
    __shared__ float2 Us[kM * kM * kNY];
    int t = threadIdx.x;
    int xx = t / kNY, yy = t % kNY;
    float accz[13];
    #pragma unroll
    for (int zi = 0; zi < 13; ++zi) accz[zi] = 0.f;

    for (int ci = 0; ci < 8; ++ci) {
        int c = c0 + ci;
        __syncthreads();
        int ck = c * kC + k;
        for (int j = t; j < kM * kNT; j += 256) e1s[j] = e1t[(size_t)ck * kM * kNT + j];
        for (int j = t; j < kM * kNX; j += 256) e2s[j] = e2t[(size_t)ck * kM * kNX + j];
        for (int j = t; j < kM * kNY; j += 256) e3s[j] = e3t[(size_t)ck * kM * kNY + j];
        for (int j = t; j < kMR; j += 256) o2s[j] = or2[(size_t)(b * kC + c) * kMR + j];
        __syncthreads();
        for (int j = t; j < kM * kM * kNY; j += 256) {
            int y = j % kNY; int pq = j / kNY;
            float2 u = make_float2(0.f, 0.f);
            #pragma unroll
            for (int m = 0; m < kM; ++m) cfma(u, o2s[pq * kM + m], e3s[m * kNY + y]);
            Us[j] = u;
        }
        __syncthreads();
        if (t < kNS) {
            float2 V[kM];
            #pragma unroll
            for (int p = 0; p < kM; ++p) {
                float2 v = make_float2(0.f, 0.f);
                #pragma unroll
                for (int q = 0; q < kM; ++q) cfma(v, Us[(p * kM + q) * kNY + yy], e2s[q * kNX + xx]);
                V[p] = v;
            }
            #pragma unroll
            for (int p = 0; p < kM; ++p) {
                #pragma unroll
                for (int zi = 0; zi < 13; ++zi) {
                    float2 e = e1s[p * kNT + z0 + zi];
                    accz[zi] = fmaf(V[p].x, e.x, accz[zi]);
                    accz[zi] = fmaf(-V[p].y, e.y, accz[zi]);
                }
            }
        }
    }
    if (t < kNS) {
        size_t base = ((size_t)(bk * 2 + blockIdx.z)) * kNF + (size_t)z0 * kNS + t;
        #pragma unroll
        for (int zi = 0; zi < 13; ++zi) P2[base + (size_t)zi * kNS] = accz[zi];
    }
}

// K8b: out[bk*kNF+f] = (P2[2bk][f] + P2[2bk+1][f]) / 7644   (overwrites poison)
__global__ __launch_bounds__(256) void k_x2red(
    const float* __restrict__ P2, float* __restrict__ outp)
{
    int id = blockIdx.x * blockDim.x + threadIdx.x;
    if (id >= kB * kC * kNF) return;
    int f = id % kNF; int bk = id / kNF;
    const float sc = 1.0f / 7644.0f;
    outp[id] = (P2[(size_t)(2 * bk) * kNF + f] + P2[(size_t)(2 * bk + 1) * kNF + f]) * sc;
}

// ---------------------------------------------------------------------------
extern "C" void kernel_launch(void* const* d_in, const int* in_sizes, int n_in,
                              void* d_out, int out_size, void* d_ws, size_t ws_size,
                              hipStream_t stream) {
    (void)in_sizes; (void)n_in; (void)out_size; (void)ws_size;
    const float* x      = (const float*)d_in[0];
    const float* wp1_re = (const float*)d_in[1];
    const float* wp1_im = (const float*)d_in[2];
    const float* wp2_re = (const float*)d_in[3];
    const float* wp2_im = (const float*)d_in[4];
    const float* wp3_re = (const float*)d_in[5];
    const float* wp3_im = (const float*)d_in[6];
    const float* wr_re  = (const float*)d_in[7];
    const float* wr_im  = (const float*)d_in[8];
    float* out = (float*)d_out;

    const size_t big = (size_t)kNIK * kNF;  // 1,956,864 complex
    float2* A   = (float2*)d_ws;            // scratch 1 (or1)
    float2* Bb  = A + big;                  // scratch 2 (alpha, then x2 partials as float)
    float2* Cc  = Bb + big;                 // H, then or2 partials, then ifft scratch
    float2* OR2 = Cc + big;                 // 55,296
    float2* r1t = OR2 + (size_t)kB * kC * kMR;
    float2* r2t = r1t + (size_t)kNIK * kM * kNT;
    float2* r3t = r2t + (size_t)kNIK * kM * kNX;
    float2* e1t = r3t + (size_t)kNIK * kM * kNY;
    float2* e2t = e1t + (size_t)kNIK * kM * kNT;
    float2* e3t = e2t + (size_t)kNIK * kM * kNX;
    float2* F39 = e3t + (size_t)kNIK * kM * kNY;
    float2* F14 = F39 + kNT * kNT;

    k_init<<<64, 256, 0, stream>>>(wp1_re, wp1_im, wp2_re, wp2_im, wp3_re, wp3_im,
                                   F39, F14, r1t, r2t, r3t, e1t, e2t, e3t);
    // forward DFT: x -> A (t-pass) -> Bb (fused xy). alpha lives in Bb.
    k_dft_t_real<<<dim3(kNIK, 3), 256, 0, stream>>>(x, F39, A);
    k_dft_xy<<<kNIK * kNT, 256, 0, stream>>>(A, F14, Bb);
    // transfer function H -> Cc; or1 -> A
    k_H<<<kNIK, 256, 0, stream>>>(wr_re, wr_im, r1t, r2t, r3t, Cc);
    k_or1<<<kNF / kFCH, 256, 0, stream>>>(Bb, Cc, A);
    // or2: partials into Cc (H dead), reduce -> OR2. Last readers of alpha (Bb).
    k_or2p<<<kB * kC * kC, 256, 0, stream>>>(Bb, wr_re, wr_im, r1t, r2t, r3t, Cc);
    k_or2red<<<(kB * kC * kMR + 255) / 256, 256, 0, stream>>>(Cc, OR2);
    // x2: partials into Bb (alpha dead; float layout, exactly 2*big floats), reduce -> out
    k_x2zp<<<dim3(kB * kC, 3, 2), 256, 0, stream>>>(OR2, e1t, e2t, e3t, (float*)Bb);
    k_x2red<<<(kB * kC * kNF + 255) / 256, 256, 0, stream>>>((const float*)Bb, out);
    // inverse FFT of or1 (in A): A -> Cc (t-pass) -> += d_out (fused xy + add)
    k_idft_t<<<dim3(kB * kC, 3), 256, 0, stream>>>(A, F39, Cc);
    k_idft_xy_final<<<kNIK * kNT, 256, 0, stream>>>(Cc, F14, out);
}

// Round 5
// 207.628 us; speedup vs baseline: 1.6969x; 1.0839x over previous
//
#include <hip/hip_runtime.h>

// Problem constants
constexpr int kB  = 16;    // batch
constexpr int kC  = 16;    // CI == CO
constexpr int kM  = 6;     // M1 == M2 == M3
constexpr int kNT = 39;
constexpr int kNX = 14;    // NXr
constexpr int kNY = 14;    // NYr
constexpr int kNS = kNX * kNY;       // 196
constexpr int kNF = kNT * kNS;       // 7644
constexpr int kNIK = kC * kC;        // 256
constexpr int kMR = kM * kM * kM;    // 216
constexpr int kFCH = 6;              // f-chunk for k_or1 (7644 = 6*1274)

__device__ __forceinline__ float2 cmul(float2 a, float2 b) {
    return make_float2(a.x * b.x - a.y * b.y, a.x * b.y + a.y * b.x);
}
__device__ __forceinline__ void cfma(float2& c, float2 a, float2 b) {
    c.x = fmaf(a.x, b.x, fmaf(-a.y, b.y, c.x));
    c.y = fmaf(a.x, b.y, fmaf(a.y, b.x, c.y));
}

// ---------------------------------------------------------------------------
// K0: DFT matrices + pole-reciprocal tables r1/r2/r3 + exp tables e1/e2/e3
// ---------------------------------------------------------------------------
__global__ __launch_bounds__(256) void k_init(
    const float* __restrict__ wp1_re, const float* __restrict__ wp1_im,
    const float* __restrict__ wp2_re, const float* __restrict__ wp2_im,
    const float* __restrict__ wp3_re, const float* __restrict__ wp3_im,
    float2* __restrict__ F39, float2* __restrict__ F14,
    float2* __restrict__ r1t, float2* __restrict__ r2t, float2* __restrict__ r3t,
    float2* __restrict__ e1t, float2* __restrict__ e2t, float2* __restrict__ e3t)
{
    const float PI2 = 6.283185307179586f;
    int tid = blockIdx.x * blockDim.x + threadIdx.x;
    int nth = gridDim.x * blockDim.x;

    for (int idx = tid; idx < kNT * kNT; idx += nth) {
        int m = idx / kNT, t = idx % kNT;
        float ang = -PI2 * (float)((m * t) % kNT) / (float)kNT;
        float s, c; sincosf(ang, &s, &c);
        F39[idx] = make_float2(c, s);
    }
    for (int idx = tid; idx < kNX * kNX; idx += nth) {
        int a = idx / kNX, b = idx % kNX;
        float ang = -PI2 * (float)((a * b) % kNX) / (float)kNX;
        float s, c; sincosf(ang, &s, &c);
        F14[idx] = make_float2(c, s);
    }
    for (int idx = tid; idx < kNIK * kM * kNT; idx += nth) {
        int z = idx % kNT; int ikp = idx / kNT;
        float wre = wp1_re[ikp], wim = wp1_im[ikp];
        float f = (z < 20 ? (float)z : (float)(z - kNT)) / (float)kNT;
        float w = PI2 * f;
        float dr = -wre, di = w - wim;
        float inv = 1.0f / (dr * dr + di * di);
        r1t[idx] = make_float2(dr * inv, -di * inv);
        float tt = (float)z;
        float er = expf(wre * tt);
        float s, c; sincosf(wim * tt, &s, &c);
        e1t[idx] = make_float2(er * c, er * s);
    }
    for (int idx = tid; idx < kNIK * kM * kNX; idx += nth) {
        int n = idx % kNX; int ikq = idx / kNX;
        float f = (n <= 6 ? (float)n : (float)(n - kNX)) * 27.0f / 14.0f;
        float w = PI2 * f;
        float tx = (float)n * (1.0f / 27.0f);
        {
            float wre = wp2_re[ikq], wim = wp2_im[ikq];
            float dr = -wre, di = w - wim;
            float inv = 1.0f / (dr * dr + di * di);
            r2t[idx] = make_float2(dr * inv, -di * inv);
            float er = expf(wre * tx);
            float s, c; sincosf(wim * tx, &s, &c);
            e2t[idx] = make_float2(er * c, er * s);
        }
        {
            float wre = wp3_re[ikq], wim = wp3_im[ikq];
            float dr = -wre, di = w - wim;
            float inv = 1.0f / (dr * dr + di * di);
            r3t[idx] = make_float2(dr * inv, -di * inv);
            float er = expf(wre * tx);
            float s, c; sincosf(wim * tx, &s, &c);
            e3t[idx] = make_float2(er * c, er * s);
        }
    }
}

// ---------------------------------------------------------------------------
// Forward t-DFT of real x, register-column form. grid (bc, 3); thread owns s.
// ---------------------------------------------------------------------------
__global__ __launch_bounds__(256) void k_dft_t_real(
    const float* __restrict__ x, const float2* __restrict__ F39, float2* __restrict__ out)
{
    int bc = blockIdx.x, mg = blockIdx.y;
    __shared__ float2 Fs[13 * kNT];
    int t = threadIdx.x;
    for (int j = t; j < 13 * kNT; j += 256)
        Fs[j] = F39[(mg * 13 + j / kNT) * kNT + (j % kNT)];
    __syncthreads();
    if (t < kNS) {
        float col[kNT];
        const float* xp = x + (size_t)bc * kNF + t;
        #pragma unroll
        for (int tt = 0; tt < kNT; ++tt) col[tt] = xp[(size_t)tt * kNS];
        for (int mi = 0; mi < 13; ++mi) {
            float2 acc = make_float2(0.f, 0.f);
            #pragma unroll
            for (int tt = 0; tt < kNT; ++tt) {
                float2 f = Fs[mi * kNT + tt];
                acc.x = fmaf(f.x, col[tt], acc.x);
                acc.y = fmaf(f.y, col[tt], acc.y);
            }
            out[((size_t)bc * kNT + mg * 13 + mi) * kNS + t] = acc;
        }
    }
}

// ---------------------------------------------------------------------------
// Inverse t-DFT (conj F), register-column form. grid (bk, 3); thread owns s.
// ---------------------------------------------------------------------------
__global__ __launch_bounds__(256) void k_idft_t(
    const float2* __restrict__ in, const float2* __restrict__ F39, float2* __restrict__ out)
{
    int bk = blockIdx.x, zg = blockIdx.y;
    __shared__ float2 Fs[13 * kNT];
    int t = threadIdx.x;
    for (int j = t; j < 13 * kNT; j += 256) {
        float2 f = F39[(zg * 13 + j / kNT) * kNT + (j % kNT)];
        f.y = -f.y;
        Fs[j] = f;
    }
    __syncthreads();
    if (t < kNS) {
        float2 col[kNT];
        const float2* ip = in + (size_t)bk * kNF + t;
        #pragma unroll
        for (int m = 0; m < kNT; ++m) col[m] = ip[(size_t)m * kNS];
        for (int zi = 0; zi < 13; ++zi) {
            float2 acc = make_float2(0.f, 0.f);
            #pragma unroll
            for (int m = 0; m < kNT; ++m) cfma(acc, Fs[zi * kNT + m], col[m]);
            out[((size_t)bk * kNT + zg * 13 + zi) * kNS + t] = acc;
        }
    }
}

// ---------------------------------------------------------------------------
// Fused forward x+y DFT on one 14x14 tile. Block per (bc*39+m).
// ---------------------------------------------------------------------------
__global__ __launch_bounds__(256) void k_dft_xy(
    const float2* __restrict__ in, const float2* __restrict__ F14, float2* __restrict__ out)
{
    int bm = blockIdx.x;
    __shared__ float2 tile[kNS];
    __shared__ float2 tmp[kNS];
    __shared__ float2 Fs[kNX * kNX];
    int t = threadIdx.x;
    if (t < kNS) tile[t] = in[(size_t)bm * kNS + t];
    if (t < kNX * kNX) Fs[t] = F14[t];
    __syncthreads();
    if (t < kNS) {
        int n2 = t / kNY, l = t % kNY;
        float2 acc = make_float2(0.f, 0.f);
        #pragma unroll
        for (int n = 0; n < kNX; ++n) cfma(acc, Fs[n2 * kNX + n], tile[n * kNY + l]);
        tmp[t] = acc;
    }
    __syncthreads();
    if (t < kNS) {
        int n = t / kNY, l2 = t % kNY;
        float2 acc = make_float2(0.f, 0.f);
        #pragma unroll
        for (int l = 0; l < kNY; ++l) cfma(acc, Fs[l2 * kNY + l], tmp[n * kNY + l]);
        out[(size_t)bm * kNS + t] = acc;
    }
}

// Fused inverse x+y DFT + take-real + scale + add into output.
__global__ __launch_bounds__(256) void k_idft_xy_final(
    const float2* __restrict__ in, const float2* __restrict__ F14, float* __restrict__ outp)
{
    int bm = blockIdx.x;
    __shared__ float2 tile[kNS];
    __shared__ float2 tmp[kNS];
    __shared__ float2 Fs[kNX * kNX];
    int t = threadIdx.x;
    if (t < kNS) tile[t] = in[(size_t)bm * kNS + t];
    if (t < kNX * kNX) { float2 f = F14[t]; f.y = -f.y; Fs[t] = f; }
    __syncthreads();
    if (t < kNS) {
        int n2 = t / kNY, l = t % kNY;
        float2 acc = make_float2(0.f, 0.f);
        #pragma unroll
        for (int n = 0; n < kNX; ++n) cfma(acc, Fs[n2 * kNX + n], tile[n * kNY + l]);
        tmp[t] = acc;
    }
    __syncthreads();
    if (t < kNS) {
        int n = t / kNY, l2 = t % kNY;
        float2 acc = make_float2(0.f, 0.f);
        #pragma unroll
        for (int l = 0; l < kNY; ++l) cfma(acc, Fs[l2 * kNY + l], tmp[n * kNY + l]);
        outp[(size_t)bm * kNS + t] += acc.x * (1.0f / 7644.0f);
    }
}

// ---------------------------------------------------------------------------
// K4: H[i,k,m,n,l] = sum_{p,q,r} wr[i,k,p,q,r] r1[m] r2[n] r3[l]; block per (i,k)
// ---------------------------------------------------------------------------
__global__ __launch_bounds__(256) void k_H(
    const float* __restrict__ wr_re, const float* __restrict__ wr_im,
    const float2* __restrict__ r1t, const float2* __restrict__ r2t,
    const float2* __restrict__ r3t, float2* __restrict__ H)
{
    int ik = blockIdx.x;
    __shared__ float2 wrs[kMR];
    __shared__ float2 r1s[kM * kNT];
    __shared__ float2 r2s[kM * kNX];
    __shared__ float2 r3s[kM * kNY];
    __shared__ float2 As[kM * kM * kNY];
    __shared__ float2 Ss[kM * kNS];
    int t = threadIdx.x;
    for (int j = t; j < kMR; j += 256)
        wrs[j] = make_float2(wr_re[ik * kMR + j], wr_im[ik * kMR + j]);
    for (int j = t; j < kM * kNT; j += 256) r1s[j] = r1t[(size_t)ik * kM * kNT + j];
    for (int j = t; j < kM * kNX; j += 256) r2s[j] = r2t[(size_t)ik * kM * kNX + j];
    for (int j = t; j < kM * kNY; j += 256) r3s[j] = r3t[(size_t)ik * kM * kNY + j];
    __syncthreads();
    for (int j = t; j < kM * kM * kNY; j += 256) {
        int l = j % kNY; int pq = j / kNY;
        float2 acc = make_float2(0.f, 0.f);
        #pragma unroll
        for (int r = 0; r < kM; ++r) cfma(acc, wrs[pq * kM + r], r3s[r * kNY + l]);
        As[j] = acc;
    }
    __syncthreads();
    for (int j = t; j < kM * kNS; j += 256) {
        int l = j % kNY; int n = (j / kNY) % kNX; int p = j / kNS;
        float2 acc = make_float2(0.f, 0.f);
        #pragma unroll
        for (int q = 0; q < kM; ++q) cfma(acc, r2s[q * kNX + n], As[(p * kM + q) * kNY + l]);
        Ss[j] = acc;
    }
    __syncthreads();
    for (int j = t; j < kNF; j += 256) {
        int m = j / kNS; int nl = j % kNS;
        float2 acc = make_float2(0.f, 0.f);
        #pragma unroll
        for (int p = 0; p < kM; ++p) cfma(acc, r1s[p * kNT + m], Ss[p * kNS + nl]);
        H[(size_t)ik * kNF + j] = acc;
    }
}

// ---------------------------------------------------------------------------
// K5: or1[b,k,f] = sum_i alpha[b,i,f] * H[i,k,f]
// f-chunked, LDS-staged (16x reuse). One block per 6 f's; thread = (b,k).
// ---------------------------------------------------------------------------
__global__ __launch_bounds__(256) void k_or1(
    const float2* __restrict__ alpha, const float2* __restrict__ H, float2* __restrict__ out)
{
    int f0 = blockIdx.x * kFCH;
    __shared__ float2 As[256 * 7 + 16];
    __shared__ float2 Hs[256 * 7 + 16];
    int t = threadIdx.x;
    {
        const float2* ap = alpha + (size_t)t * kNF + f0;
        const float2* hp = H + (size_t)t * kNF + f0;
        int base = t * 7 + (t >> 4);
        #pragma unroll
        for (int j = 0; j < kFCH; ++j) {
            As[base + j] = ap[j];
            Hs[base + j] = hp[j];
        }
    }
    __syncthreads();
    int b = t >> 4, k = t & 15;
    float2 acc[kFCH];
    #pragma unroll
    for (int j = 0; j < kFCH; ++j) acc[j] = make_float2(0.f, 0.f);
    #pragma unroll
    for (int i = 0; i < kC; ++i) {
        int ai = (b * 16 + i) * 7 + b;
        int hi = (i * 16 + k) * 7 + i;
        #pragma unroll
        for (int j = 0; j < kFCH; ++j) cfma(acc[j], As[ai + j], Hs[hi + j]);
    }
    float2* op = out + (size_t)t * kNF + f0;
    #pragma unroll
    for (int j = 0; j < kFCH; ++j) op[j] = acc[j];
}

// ---------------------------------------------------------------------------
// K7a: partial or2 per (b-pair,k,i). Tables (ik) amortized across 2 batches.
// P[((b*16+k)*16+i)*216+t] = wr[ik,t] * G[b,i,k,t]
// ---------------------------------------------------------------------------
__global__ __launch_bounds__(256) void k_or2p(
    const float2* __restrict__ alpha,
    const float* __restrict__ wr_re, const float* __restrict__ wr_im,
    const float2* __restrict__ r1t, const float2* __restrict__ r2t,
    const float2* __restrict__ r3t, float2* __restrict__ P)
{
    int blk = blockIdx.x;            // (pb*16 + k)*16 + i
    int i = blk % kC; int rest = blk / kC;
    int k = rest % kC; int pb = rest / kC;
    int b0 = 2 * pb, b1 = 2 * pb + 1;
    int ik = i * kC + k;
    __shared__ float2 r1s[kM * kNT];
    __shared__ float2 r2s[kM * kNX];
    __shared__ float2 r3s[kM * kNY];
    __shared__ float2 wrs[kMR];
    __shared__ float2 T1a[kM * kNS];
    __shared__ float2 T1b[kM * kNS];
    __shared__ float2 T2a[kM * kM * kNY];
    __shared__ float2 T2b[kM * kM * kNY];
    int t = threadIdx.x;
    for (int j = t; j < kM * kNT; j += 256) r1s[j] = r1t[(size_t)ik * kM * kNT + j];
    for (int j = t; j < kM * kNX; j += 256) r2s[j] = r2t[(size_t)ik * kM * kNX + j];
    for (int j = t; j < kM * kNY; j += 256) r3s[j] = r3t[(size_t)ik * kM * kNY + j];
    for (int j = t; j < kMR; j += 256)
        wrs[j] = make_float2(wr_re[ik * kMR + j], wr_im[ik * kMR + j]);
    __syncthreads();
    if (t < kNS) {
        float2 c0 = make_float2(0.f, 0.f), c1 = c0, c2 = c0, c3 = c0, c4 = c0, c5 = c0;
        float2 d0 = c0, d1 = c0, d2 = c0, d3 = c0, d4 = c0, d5 = c0;
        const float2* ap0 = alpha + (size_t)(b0 * kC + i) * kNF + t;
        const float2* ap1 = alpha + (size_t)(b1 * kC + i) * kNF + t;
        for (int m = 0; m < kNT; ++m) {
            float2 a0 = ap0[(size_t)m * kNS];
            float2 a1 = ap1[(size_t)m * kNS];
            float2 r;
            r = r1s[0 * kNT + m]; cfma(c0, a0, r); cfma(d0, a1, r);
            r = r1s[1 * kNT + m]; cfma(c1, a0, r); cfma(d1, a1, r);
            r = r1s[2 * kNT + m]; cfma(c2, a0, r); cfma(d2, a1, r);
            r = r1s[3 * kNT + m]; cfma(c3, a0, r); cfma(d3, a1, r);
            r = r1s[4 * kNT + m]; cfma(c4, a0, r); cfma(d4, a1, r);
            r = r1s[5 * kNT + m]; cfma(c5, a0, r); cfma(d5, a1, r);
        }
        T1a[0 * kNS + t] = c0; T1a[1 * kNS + t] = c1; T1a[2 * kNS + t] = c2;
        T1a[3 * kNS + t] = c3; T1a[4 * kNS + t] = c4; T1a[5 * kNS + t] = c5;
        T1b[0 * kNS + t] = d0; T1b[1 * kNS + t] = d1; T1b[2 * kNS + t] = d2;
        T1b[3 * kNS + t] = d3; T1b[4 * kNS + t] = d4; T1b[5 * kNS + t] = d5;
    }
    __syncthreads();
    for (int j = t; j < kM * kM * kNY; j += 256) {
        int l = j % kNY; int q = (j / kNY) % kM; int p = j / (kNY * kM);
        float2 a2 = make_float2(0.f, 0.f);
        float2 b2 = make_float2(0.f, 0.f);
        #pragma unroll
        for (int n = 0; n < kNX; ++n) {
            float2 r = r2s[q * kNX + n];
            cfma(a2, T1a[p * kNS + n * kNY + l], r);
            cfma(b2, T1b[p * kNS + n * kNY + l], r);
        }
        T2a[j] = a2;
        T2b[j] = b2;
    }
    __syncthreads();
    if (t < kMR) {
        int r = t % kM; int q = (t / kM) % kM; int p = t / (kM * kM);
        float2 t3a = make_float2(0.f, 0.f);
        float2 t3b = make_float2(0.f, 0.f);
        #pragma unroll
        for (int l = 0; l < kNY; ++l) {
            float2 rr = r3s[r * kNY + l];
            cfma(t3a, T2a[(p * kM + q) * kNY + l], rr);
            cfma(t3b, T2b[(p * kM + q) * kNY + l], rr);
        }
        float2 w = wrs[t];
        P[((size_t)(b0 * kC + k) * kC + i) * kMR + t] = cmul(w, t3a);
        P[((size_t)(b1 * kC + k) * kC + i) * kMR + t] = cmul(w, t3b);
    }
}

// K7b: or2[bk][t] = -sum_i P[(bk*16+i)*216+t]
__global__ __launch_bounds__(256) void k_or2red(
    const float2* __restrict__ P, float2* __restrict__ or2)
{
    int id = blockIdx.x * blockDim.x + threadIdx.x;
    if (id >= kB * kC * kMR) return;
    int t = id % kMR; int bk = id / kMR;
    float2 s = make_float2(0.f, 0.f);
    #pragma unroll
    for (int i = 0; i < kC; ++i) {
        float2 v = P[((size_t)bk * kC + i) * kMR + t];
        s.x += v.x; s.y += v.y;
    }
    or2[id] = make_float2(-s.x, -s.y);
}

// ---------------------------------------------------------------------------
// K8: x2, 2 batches per block. grid (8 b-pairs * 16 k, 3 zg); 16 c's in-loop.
// Writes directly (overwrite) to d_out — covers every element exactly once.
// ---------------------------------------------------------------------------
__global__ __launch_bounds__(256) void k_x2bp(
    const float2* __restrict__ or2,
    const float2* __restrict__ e1t, const float2* __restrict__ e2t,
    const float2* __restrict__ e3t, float* __restrict__ outp)
{
    int bx = blockIdx.x;
    int k = bx & 15, pb = bx >> 4;
    int b0 = 2 * pb, b1 = 2 * pb + 1;
    int z0 = blockIdx.y * 13;
    __shared__ float2 e1s[kM * 13];        // [p][zi] window
    __shared__ float2 e2s[kNX * kM];       // [x][q]
    __shared__ float2 e3s[kM * kNY];       // [m][y]
    __shared__ float2 o2s0[kMR];
    __shared__ float2 o2s1[kMR];
    __shared__ float2 Us0[kM * kM * kNY];  // [p][q][y]
    __shared__ float2 Us1[kM * kM * kNY];
    int t = threadIdx.x;
    int xx = t / kNY, yy = t % kNY;
    float accz0[13], accz1[13];
    #pragma unroll
    for (int zi = 0; zi < 13; ++zi) { accz0[zi] = 0.f; accz1[zi] = 0.f; }

    for (int c = 0; c < kC; ++c) {
        __syncthreads();
        int ck = c * kC + k;
        if (t < kM * 13) {
            int p = t / 13, zi = t % 13;
            e1s[t] = e1t[(size_t)ck * (kM * kNT) + p * kNT + z0 + zi];
        }
        if (t < kNX * kM) {
            int x = t / kM, q = t % kM;
            e2s[t] = e2t[(size_t)ck * (kM * kNX) + q * kNX + x];
        }
        if (t < kM * kNY) e3s[t] = e3t[(size_t)ck * (kM * kNY) + t];
        if (t < kMR) {
            o2s0[t] = or2[(size_t)(b0 * kC + c) * kMR + t];
            o2s1[t] = or2[(size_t)(b1 * kC + c) * kMR + t];
        }
        __syncthreads();
        for (int j = t; j < kM * kM * kNY; j += 256) {
            int y = j % kNY; int pq = j / kNY;
            float2 u0 = make_float2(0.f, 0.f);
            float2 u1 = make_float2(0.f, 0.f);
            #pragma unroll
            for (int m = 0; m < kM; ++m) {
                float2 e = e3s[m * kNY + y];
                cfma(u0, o2s0[pq * kM + m], e);
                cfma(u1, o2s1[pq * kM + m], e);
            }
            Us0[j] = u0;
            Us1[j] = u1;
        }
        __syncthreads();
        if (t < kNS) {
            float2 e2r[kM];
            #pragma unroll
            for (int q = 0; q < kM; ++q) e2r[q] = e2s[xx * kM + q];
            #pragma unroll
            for (int p = 0; p < kM; ++p) {
                float2 v0 = make_float2(0.f, 0.f);
                float2 v1 = make_float2(0.f, 0.f);
                #pragma unroll
                for (int q = 0; q < kM; ++q) {
                    cfma(v0, Us0[(p * kM + q) * kNY + yy], e2r[q]);
                    cfma(v1, Us1[(p * kM + q) * kNY + yy], e2r[q]);
                }
                #pragma unroll
                for (int zi = 0; zi < 13; ++zi) {
                    float2 e = e1s[p * 13 + zi];
                    accz0[zi] = fmaf(v0.x, e.x, fmaf(-v0.y, e.y, accz0[zi]));
                    accz1[zi] = fmaf(v1.x, e.x, fmaf(-v1.y, e.y, accz1[zi]));
                }
            }
        }
    }
    if (t < kNS) {
        const float sc = 1.0f / 7644.0f;
        size_t base0 = ((size_t)(b0 * kC + k) * kNT + z0) * kNS + t;
        size_t base1 = ((size_t)(b1 * kC + k) * kNT + z0) * kNS + t;
        #pragma unroll
        for (int zi = 0; zi < 13; ++zi) {
            outp[base0 + (size_t)zi * kNS] = accz0[zi] * sc;
            outp[base1 + (size_t)zi * kNS] = accz1[zi] * sc;
        }
    }
}

// ---------------------------------------------------------------------------
extern "C" void kernel_launch(void* const* d_in, const int* in_sizes, int n_in,
                              void* d_out, int out_size, void* d_ws, size_t ws_size,
                              hipStream_t stream) {
    (void)in_sizes; (void)n_in; (void)out_size; (void)ws_size;
    const float* x      = (const float*)d_in[0];
    const float* wp1_re = (const float*)d_in[1];
    const float* wp1_im = (const float*)d_in[2];
    const float* wp2_re = (const float*)d_in[3];
    const float* wp2_im = (const float*)d_in[4];
    const float* wp3_re = (const float*)d_in[5];
    const float* wp3_im = (const float*)d_in[6];
    const float* wr_re  = (const float*)d_in[7];
    const float* wr_im  = (const float*)d_in[8];
    float* out = (float*)d_out;

    const size_t big = (size_t)kNIK * kNF;  // 1,956,864 complex
    float2* A   = (float2*)d_ws;            // scratch 1 (or1)
    float2* Bb  = A + big;                  // scratch 2 (alpha)
    float2* Cc  = Bb + big;                 // H, then or2 partials, then ifft scratch
    float2* OR2 = Cc + big;                 // 55,296
    float2* r1t = OR2 + (size_t)kB * kC * kMR;
    float2* r2t = r1t + (size_t)kNIK * kM * kNT;
    float2* r3t = r2t + (size_t)kNIK * kM * kNX;
    float2* e1t = r3t + (size_t)kNIK * kM * kNY;
    float2* e2t = e1t + (size_t)kNIK * kM * kNT;
    float2* e3t = e2t + (size_t)kNIK * kM * kNX;
    float2* F39 = e3t + (size_t)kNIK * kM * kNY;
    float2* F14 = F39 + kNT * kNT;

    k_init<<<64, 256, 0, stream>>>(wp1_re, wp1_im, wp2_re, wp2_im, wp3_re, wp3_im,
                                   F39, F14, r1t, r2t, r3t, e1t, e2t, e3t);
    // forward DFT: x -> A (t-pass) -> Bb (fused xy). alpha lives in Bb.
    k_dft_t_real<<<dim3(kNIK, 3), 256, 0, stream>>>(x, F39, A);
    k_dft_xy<<<kNIK * kNT, 256, 0, stream>>>(A, F14, Bb);
    // transfer function H -> Cc; or1 -> A
    k_H<<<kNIK, 256, 0, stream>>>(wr_re, wr_im, r1t, r2t, r3t, Cc);
    k_or1<<<kNF / kFCH, 256, 0, stream>>>(Bb, Cc, A);
    // or2: partials into Cc (H dead), reduce -> OR2. Last readers of alpha (Bb).
    k_or2p<<<(kB / 2) * kC * kC, 256, 0, stream>>>(Bb, wr_re, wr_im, r1t, r2t, r3t, Cc);
    k_or2red<<<(kB * kC * kMR + 255) / 256, 256, 0, stream>>>(Cc, OR2);
    // x2 -> d_out directly (overwrite; every element written exactly once)
    k_x2bp<<<dim3((kB / 2) * kC, 3), 256, 0, stream>>>(OR2, e1t, e2t, e3t, out);
    // inverse FFT of or1 (in A): A -> Cc (t-pass) -> += d_out (fused xy + add)
    k_idft_t<<<dim3(kB * kC, 3), 256, 0, stream>>>(A, F39, Cc);
    k_idft_xy_final<<<kNIK * kNT, 256, 0, stream>>>(Cc, F14, out);
}

// Round 6
// 206.971 us; speedup vs baseline: 1.7023x; 1.0032x over previous
//
#include <hip/hip_runtime.h>

// Problem constants
constexpr int kB  = 16;    // batch
constexpr int kC  = 16;    // CI == CO
constexpr int kM  = 6;     // M1 == M2 == M3
constexpr int kNT = 39;
constexpr int kNX = 14;    // NXr
constexpr int kNY = 14;    // NYr
constexpr int kNS = kNX * kNY;       // 196
constexpr int kNF = kNT * kNS;       // 7644
constexpr int kNIK = kC * kC;        // 256
constexpr int kMR = kM * kM * kM;    // 216
constexpr int kFCH = 6;              // f-chunk for k_or1 (7644 = 6*1274)

__device__ __forceinline__ float2 cmul(float2 a, float2 b) {
    return make_float2(a.x * b.x - a.y * b.y, a.x * b.y + a.y * b.x);
}
__device__ __forceinline__ void cfma(float2& c, float2 a, float2 b) {
    c.x = fmaf(a.x, b.x, fmaf(-a.y, b.y, c.x));
    c.y = fmaf(a.x, b.y, fmaf(a.y, b.x, c.y));
}

// ---------------------------------------------------------------------------
// K0: DFT matrices + pole-reciprocal tables r1/r2/r3 + exp tables e1/e2/e3
// ---------------------------------------------------------------------------
__global__ __launch_bounds__(256) void k_init(
    const float* __restrict__ wp1_re, const float* __restrict__ wp1_im,
    const float* __restrict__ wp2_re, const float* __restrict__ wp2_im,
    const float* __restrict__ wp3_re, const float* __restrict__ wp3_im,
    float2* __restrict__ F39, float2* __restrict__ F14,
    float2* __restrict__ r1t, float2* __restrict__ r2t, float2* __restrict__ r3t,
    float2* __restrict__ e1t, float2* __restrict__ e2t, float2* __restrict__ e3t)
{
    const float PI2 = 6.283185307179586f;
    int tid = blockIdx.x * blockDim.x + threadIdx.x;
    int nth = gridDim.x * blockDim.x;

    for (int idx = tid; idx < kNT * kNT; idx += nth) {
        int m = idx / kNT, t = idx % kNT;
        float ang = -PI2 * (float)((m * t) % kNT) / (float)kNT;
        float s, c; sincosf(ang, &s, &c);
        F39[idx] = make_float2(c, s);
    }
    for (int idx = tid; idx < kNX * kNX; idx += nth) {
        int a = idx / kNX, b = idx % kNX;
        float ang = -PI2 * (float)((a * b) % kNX) / (float)kNX;
        float s, c; sincosf(ang, &s, &c);
        F14[idx] = make_float2(c, s);
    }
    for (int idx = tid; idx < kNIK * kM * kNT; idx += nth) {
        int z = idx % kNT; int ikp = idx / kNT;
        float wre = wp1_re[ikp], wim = wp1_im[ikp];
        float f = (z < 20 ? (float)z : (float)(z - kNT)) / (float)kNT;
        float w = PI2 * f;
        float dr = -wre, di = w - wim;
        float inv = 1.0f / (dr * dr + di * di);
        r1t[idx] = make_float2(dr * inv, -di * inv);
        float tt = (float)z;
        float er = expf(wre * tt);
        float s, c; sincosf(wim * tt, &s, &c);
        e1t[idx] = make_float2(er * c, er * s);
    }
    for (int idx = tid; idx < kNIK * kM * kNX; idx += nth) {
        int n = idx % kNX; int ikq = idx / kNX;
        float f = (n <= 6 ? (float)n : (float)(n - kNX)) * 27.0f / 14.0f;
        float w = PI2 * f;
        float tx = (float)n * (1.0f / 27.0f);
        {
            float wre = wp2_re[ikq], wim = wp2_im[ikq];
            float dr = -wre, di = w - wim;
            float inv = 1.0f / (dr * dr + di * di);
            r2t[idx] = make_float2(dr * inv, -di * inv);
            float er = expf(wre * tx);
            float s, c; sincosf(wim * tx, &s, &c);
            e2t[idx] = make_float2(er * c, er * s);
        }
        {
            float wre = wp3_re[ikq], wim = wp3_im[ikq];
            float dr = -wre, di = w - wim;
            float inv = 1.0f / (dr * dr + di * di);
            r3t[idx] = make_float2(dr * inv, -di * inv);
            float er = expf(wre * tx);
            float s, c; sincosf(wim * tx, &s, &c);
            e3t[idx] = make_float2(er * c, er * s);
        }
    }
}

// ---------------------------------------------------------------------------
// Forward t-DFT of real x, register-column form. grid (bc, 3); thread owns s.
// ---------------------------------------------------------------------------
__global__ __launch_bounds__(256) void k_dft_t_real(
    const float* __restrict__ x, const float2* __restrict__ F39, float2* __restrict__ out)
{
    int bc = blockIdx.x, mg = blockIdx.y;
    __shared__ float2 Fs[13 * kNT];
    int t = threadIdx.x;
    for (int j = t; j < 13 * kNT; j += 256)
        Fs[j] = F39[(mg * 13 + j / kNT) * kNT + (j % kNT)];
    __syncthreads();
    if (t < kNS) {
        float col[kNT];
        const float* xp = x + (size_t)bc * kNF + t;
        #pragma unroll
        for (int tt = 0; tt < kNT; ++tt) col[tt] = xp[(size_t)tt * kNS];
        for (int mi = 0; mi < 13; ++mi) {
            float2 acc = make_float2(0.f, 0.f);
            #pragma unroll
            for (int tt = 0; tt < kNT; ++tt) {
                float2 f = Fs[mi * kNT + tt];
                acc.x = fmaf(f.x, col[tt], acc.x);
                acc.y = fmaf(f.y, col[tt], acc.y);
            }
            out[((size_t)bc * kNT + mg * 13 + mi) * kNS + t] = acc;
        }
    }
}

// ---------------------------------------------------------------------------
// Inverse t-DFT (conj F), register-column form. grid (bk, 3); thread owns s.
// ---------------------------------------------------------------------------
__global__ __launch_bounds__(256) void k_idft_t(
    const float2* __restrict__ in, const float2* __restrict__ F39, float2* __restrict__ out)
{
    int bk = blockIdx.x, zg = blockIdx.y;
    __shared__ float2 Fs[13 * kNT];
    int t = threadIdx.x;
    for (int j = t; j < 13 * kNT; j += 256) {
        float2 f = F39[(zg * 13 + j / kNT) * kNT + (j % kNT)];
        f.y = -f.y;
        Fs[j] = f;
    }
    __syncthreads();
    if (t < kNS) {
        float2 col[kNT];
        const float2* ip = in + (size_t)bk * kNF + t;
        #pragma unroll
        for (int m = 0; m < kNT; ++m) col[m] = ip[(size_t)m * kNS];
        for (int zi = 0; zi < 13; ++zi) {
            float2 acc = make_float2(0.f, 0.f);
            #pragma unroll
            for (int m = 0; m < kNT; ++m) cfma(acc, Fs[zi * kNT + m], col[m]);
            out[((size_t)bk * kNT + zg * 13 + zi) * kNS + t] = acc;
        }
    }
}

// ---------------------------------------------------------------------------
// Fused forward x+y DFT on one 14x14 tile. Block per (bc*39+m).
// ---------------------------------------------------------------------------
__global__ __launch_bounds__(256) void k_dft_xy(
    const float2* __restrict__ in, const float2* __restrict__ F14, float2* __restrict__ out)
{
    int bm = blockIdx.x;
    __shared__ float2 tile[kNS];
    __shared__ float2 tmp[kNS];
    __shared__ float2 Fs[kNX * kNX];
    int t = threadIdx.x;
    if (t < kNS) tile[t] = in[(size_t)bm * kNS + t];
    if (t < kNX * kNX) Fs[t] = F14[t];
    __syncthreads();
    if (t < kNS) {
        int n2 = t / kNY, l = t % kNY;
        float2 acc = make_float2(0.f, 0.f);
        #pragma unroll
        for (int n = 0; n < kNX; ++n) cfma(acc, Fs[n2 * kNX + n], tile[n * kNY + l]);
        tmp[t] = acc;
    }
    __syncthreads();
    if (t < kNS) {
        int n = t / kNY, l2 = t % kNY;
        float2 acc = make_float2(0.f, 0.f);
        #pragma unroll
        for (int l = 0; l < kNY; ++l) cfma(acc, Fs[l2 * kNY + l], tmp[n * kNY + l]);
        out[(size_t)bm * kNS + t] = acc;
    }
}

// Fused inverse x+y DFT + take-real + scale + add into output.
__global__ __launch_bounds__(256) void k_idft_xy_final(
    const float2* __restrict__ in, const float2* __restrict__ F14, float* __restrict__ outp)
{
    int bm = blockIdx.x;
    __shared__ float2 tile[kNS];
    __shared__ float2 tmp[kNS];
    __shared__ float2 Fs[kNX * kNX];
    int t = threadIdx.x;
    if (t < kNS) tile[t] = in[(size_t)bm * kNS + t];
    if (t < kNX * kNX) { float2 f = F14[t]; f.y = -f.y; Fs[t] = f; }
    __syncthreads();
    if (t < kNS) {
        int n2 = t / kNY, l = t % kNY;
        float2 acc = make_float2(0.f, 0.f);
        #pragma unroll
        for (int n = 0; n < kNX; ++n) cfma(acc, Fs[n2 * kNX + n], tile[n * kNY + l]);
        tmp[t] = acc;
    }
    __syncthreads();
    if (t < kNS) {
        int n = t / kNY, l2 = t % kNY;
        float2 acc = make_float2(0.f, 0.f);
        #pragma unroll
        for (int l = 0; l < kNY; ++l) cfma(acc, Fs[l2 * kNY + l], tmp[n * kNY + l]);
        outp[(size_t)bm * kNS + t] += acc.x * (1.0f / 7644.0f);
    }
}

// ---------------------------------------------------------------------------
// K4: H[i,k,m,n,l] = sum_{p,q,r} wr[i,k,p,q,r] r1[m] r2[n] r3[l]; block per (i,k)
// ---------------------------------------------------------------------------
__global__ __launch_bounds__(256) void k_H(
    const float* __restrict__ wr_re, const float* __restrict__ wr_im,
    const float2* __restrict__ r1t, const float2* __restrict__ r2t,
    const float2* __restrict__ r3t, float2* __restrict__ H)
{
    int ik = blockIdx.x;
    __shared__ float2 wrs[kMR];
    __shared__ float2 r1s[kM * kNT];
    __shared__ float2 r2s[kM * kNX];
    __shared__ float2 r3s[kM * kNY];
    __shared__ float2 As[kM * kM * kNY];
    __shared__ float2 Ss[kM * kNS];
    int t = threadIdx.x;
    for (int j = t; j < kMR; j += 256)
        wrs[j] = make_float2(wr_re[ik * kMR + j], wr_im[ik * kMR + j]);
    for (int j = t; j < kM * kNT; j += 256) r1s[j] = r1t[(size_t)ik * kM * kNT + j];
    for (int j = t; j < kM * kNX; j += 256) r2s[j] = r2t[(size_t)ik * kM * kNX + j];
    for (int j = t; j < kM * kNY; j += 256) r3s[j] = r3t[(size_t)ik * kM * kNY + j];
    __syncthreads();
    for (int j = t; j < kM * kM * kNY; j += 256) {
        int l = j % kNY; int pq = j / kNY;
        float2 acc = make_float2(0.f, 0.f);
        #pragma unroll
        for (int r = 0; r < kM; ++r) cfma(acc, wrs[pq * kM + r], r3s[r * kNY + l]);
        As[j] = acc;
    }
    __syncthreads();
    for (int j = t; j < kM * kNS; j += 256) {
        int l = j % kNY; int n = (j / kNY) % kNX; int p = j / kNS;
        float2 acc = make_float2(0.f, 0.f);
        #pragma unroll
        for (int q = 0; q < kM; ++q) cfma(acc, r2s[q * kNX + n], As[(p * kM + q) * kNY + l]);
        Ss[j] = acc;
    }
    __syncthreads();
    for (int j = t; j < kNF; j += 256) {
        int m = j / kNS; int nl = j % kNS;
        float2 acc = make_float2(0.f, 0.f);
        #pragma unroll
        for (int p = 0; p < kM; ++p) cfma(acc, r1s[p * kNT + m], Ss[p * kNS + nl]);
        H[(size_t)ik * kNF + j] = acc;
    }
}

// ---------------------------------------------------------------------------
// K5: or1[b,k,f] = sum_i alpha[b,i,f] * H[i,k,f]
// f-chunked, LDS-staged (16x reuse). One block per 6 f's; thread = (b,k).
// ---------------------------------------------------------------------------
__global__ __launch_bounds__(256) void k_or1(
    const float2* __restrict__ alpha, const float2* __restrict__ H, float2* __restrict__ out)
{
    int f0 = blockIdx.x * kFCH;
    __shared__ float2 As[256 * 7 + 16];
    __shared__ float2 Hs[256 * 7 + 16];
    int t = threadIdx.x;
    {
        const float2* ap = alpha + (size_t)t * kNF + f0;
        const float2* hp = H + (size_t)t * kNF + f0;
        int base = t * 7 + (t >> 4);
        #pragma unroll
        for (int j = 0; j < kFCH; ++j) {
            As[base + j] = ap[j];
            Hs[base + j] = hp[j];
        }
    }
    __syncthreads();
    int b = t >> 4, k = t & 15;
    float2 acc[kFCH];
    #pragma unroll
    for (int j = 0; j < kFCH; ++j) acc[j] = make_float2(0.f, 0.f);
    #pragma unroll
    for (int i = 0; i < kC; ++i) {
        int ai = (b * 16 + i) * 7 + b;
        int hi = (i * 16 + k) * 7 + i;
        #pragma unroll
        for (int j = 0; j < kFCH; ++j) cfma(acc[j], As[ai + j], Hs[hi + j]);
    }
    float2* op = out + (size_t)t * kNF + f0;
    #pragma unroll
    for (int j = 0; j < kFCH; ++j) op[j] = acc[j];
}

// ---------------------------------------------------------------------------
// K7a: partial or2 per (b-pair,k,i). Tables (ik) amortized across 2 batches.
// P[((b*16+k)*16+i)*216+t] = wr[ik,t] * G[b,i,k,t]
// ---------------------------------------------------------------------------
__global__ __launch_bounds__(256) void k_or2p(
    const float2* __restrict__ alpha,
    const float* __restrict__ wr_re, const float* __restrict__ wr_im,
    const float2* __restrict__ r1t, const float2* __restrict__ r2t,
    const float2* __restrict__ r3t, float2* __restrict__ P)
{
    int blk = blockIdx.x;            // (pb*16 + k)*16 + i
    int i = blk % kC; int rest = blk / kC;
    int k = rest % kC; int pb = rest / kC;
    int b0 = 2 * pb, b1 = 2 * pb + 1;
    int ik = i * kC + k;
    __shared__ float2 r1s[kM * kNT];
    __shared__ float2 r2s[kM * kNX];
    __shared__ float2 r3s[kM * kNY];
    __shared__ float2 wrs[kMR];
    __shared__ float2 T1a[kM * kNS];
    __shared__ float2 T1b[kM * kNS];
    __shared__ float2 T2a[kM * kM * kNY];
    __shared__ float2 T2b[kM * kM * kNY];
    int t = threadIdx.x;
    for (int j = t; j < kM * kNT; j += 256) r1s[j] = r1t[(size_t)ik * kM * kNT + j];
    for (int j = t; j < kM * kNX; j += 256) r2s[j] = r2t[(size_t)ik * kM * kNX + j];
    for (int j = t; j < kM * kNY; j += 256) r3s[j] = r3t[(size_t)ik * kM * kNY + j];
    for (int j = t; j < kMR; j += 256)
        wrs[j] = make_float2(wr_re[ik * kMR + j], wr_im[ik * kMR + j]);
    __syncthreads();
    if (t < kNS) {
        float2 c0 = make_float2(0.f, 0.f), c1 = c0, c2 = c0, c3 = c0, c4 = c0, c5 = c0;
        float2 d0 = c0, d1 = c0, d2 = c0, d3 = c0, d4 = c0, d5 = c0;
        const float2* ap0 = alpha + (size_t)(b0 * kC + i) * kNF + t;
        const float2* ap1 = alpha + (size_t)(b1 * kC + i) * kNF + t;
        for (int m = 0; m < kNT; ++m) {
            float2 a0 = ap0[(size_t)m * kNS];
            float2 a1 = ap1[(size_t)m * kNS];
            float2 r;
            r = r1s[0 * kNT + m]; cfma(c0, a0, r); cfma(d0, a1, r);
            r = r1s[1 * kNT + m]; cfma(c1, a0, r); cfma(d1, a1, r);
            r = r1s[2 * kNT + m]; cfma(c2, a0, r); cfma(d2, a1, r);
            r = r1s[3 * kNT + m]; cfma(c3, a0, r); cfma(d3, a1, r);
            r = r1s[4 * kNT + m]; cfma(c4, a0, r); cfma(d4, a1, r);
            r = r1s[5 * kNT + m]; cfma(c5, a0, r); cfma(d5, a1, r);
        }
        T1a[0 * kNS + t] = c0; T1a[1 * kNS + t] = c1; T1a[2 * kNS + t] = c2;
        T1a[3 * kNS + t] = c3; T1a[4 * kNS + t] = c4; T1a[5 * kNS + t] = c5;
        T1b[0 * kNS + t] = d0; T1b[1 * kNS + t] = d1; T1b[2 * kNS + t] = d2;
        T1b[3 * kNS + t] = d3; T1b[4 * kNS + t] = d4; T1b[5 * kNS + t] = d5;
    }
    __syncthreads();
    for (int j = t; j < kM * kM * kNY; j += 256) {
        int l = j % kNY; int q = (j / kNY) % kM; int p = j / (kNY * kM);
        float2 a2 = make_float2(0.f, 0.f);
        float2 b2 = make_float2(0.f, 0.f);
        #pragma unroll
        for (int n = 0; n < kNX; ++n) {
            float2 r = r2s[q * kNX + n];
            cfma(a2, T1a[p * kNS + n * kNY + l], r);
            cfma(b2, T1b[p * kNS + n * kNY + l], r);
        }
        T2a[j] = a2;
        T2b[j] = b2;
    }
    __syncthreads();
    if (t < kMR) {
        int r = t % kM; int q = (t / kM) % kM; int p = t / (kM * kM);
        float2 t3a = make_float2(0.f, 0.f);
        float2 t3b = make_float2(0.f, 0.f);
        #pragma unroll
        for (int l = 0; l < kNY; ++l) {
            float2 rr = r3s[r * kNY + l];
            cfma(t3a, T2a[(p * kM + q) * kNY + l], rr);
            cfma(t3b, T2b[(p * kM + q) * kNY + l], rr);
        }
        float2 w = wrs[t];
        P[((size_t)(b0 * kC + k) * kC + i) * kMR + t] = cmul(w, t3a);
        P[((size_t)(b1 * kC + k) * kC + i) * kMR + t] = cmul(w, t3b);
    }
}

// K7b: or2[bk][t] = -sum_i P[(bk*16+i)*216+t]
__global__ __launch_bounds__(256) void k_or2red(
    const float2* __restrict__ P, float2* __restrict__ or2)
{
    int id = blockIdx.x * blockDim.x + threadIdx.x;
    if (id >= kB * kC * kMR) return;
    int t = id % kMR; int bk = id / kMR;
    float2 s = make_float2(0.f, 0.f);
    #pragma unroll
    for (int i = 0; i < kC; ++i) {
        float2 v = P[((size_t)bk * kC + i) * kMR + t];
        s.x += v.x; s.y += v.y;
    }
    or2[id] = make_float2(-s.x, -s.y);
}

// ---------------------------------------------------------------------------
// K8: x2 fully-fused. One block per (b,k). ALL tables staged in LDS once:
//   o2s  [c][216]      27.6 KB   (or2 rows for this b, all c)
//   e1s  [c][p][z=39]  29.9 KB
//   e2a  [c][q][x=14]  10.75 KB
//   e3a  [c][m][y=14]  10.75 KB
//   UsD  [2][504]       8.1 KB   (double-buffered per-c Us tile)
// c-loop: compute Us for c+1 into spare slot while V/z-phase consumes slot c.
// One barrier per c. 39 z-accumulators in registers. Zero global traffic
// inside the loop. Writes d_out (overwrite, full coverage).
// ---------------------------------------------------------------------------
__global__ __launch_bounds__(256) void k_x2f(
    const float2* __restrict__ or2,
    const float2* __restrict__ e1t, const float2* __restrict__ e2t,
    const float2* __restrict__ e3t, float* __restrict__ outp)
{
    int bx = blockIdx.x;
    int k = bx & 15, b = bx >> 4;
    __shared__ float2 o2s[kC * kMR];        // [c][pq*6+m]
    __shared__ float2 e1s[kC * kM * kNT];   // [c][p][z]
    __shared__ float2 e2a[kC * kM * kNX];   // [c][q][x]
    __shared__ float2 e3a[kC * kM * kNY];   // [c][m][y]
    __shared__ float2 UsD[2][kM * kM * kNY];
    int t = threadIdx.x;
    int xx = t / kNY, yy = t % kNY;

    // stage everything (coalesced)
    for (int j = t; j < kC * kMR; j += 256) {
        int c = j / kMR, u = j % kMR;
        o2s[j] = or2[(size_t)(b * kC + c) * kMR + u];
    }
    for (int j = t; j < kC * kM * kNT; j += 256) {
        int c = j / (kM * kNT), r = j % (kM * kNT);
        e1s[j] = e1t[(size_t)(c * kC + k) * (kM * kNT) + r];
    }
    for (int j = t; j < kC * kM * kNX; j += 256) {
        int c = j / (kM * kNX), r = j % (kM * kNX);
        e2a[j] = e2t[(size_t)(c * kC + k) * (kM * kNX) + r];
    }
    for (int j = t; j < kC * kM * kNY; j += 256) {
        int c = j / (kM * kNY), r = j % (kM * kNY);
        e3a[j] = e3t[(size_t)(c * kC + k) * (kM * kNY) + r];
    }
    __syncthreads();

    // Us for c=0 into slot 0
    for (int j = t; j < kM * kM * kNY; j += 256) {
        int y = j % kNY; int pq = j / kNY;
        float2 u = make_float2(0.f, 0.f);
        #pragma unroll
        for (int m = 0; m < kM; ++m)
            cfma(u, o2s[pq * kM + m], e3a[m * kNY + y]);
        UsD[0][j] = u;
    }
    __syncthreads();

    float accz[kNT];
    #pragma unroll
    for (int z = 0; z < kNT; ++z) accz[z] = 0.f;

    for (int c = 0; c < kC; ++c) {
        int cur = c & 1;
        // pipeline: compute Us for c+1 into the other slot
        if (c < kC - 1) {
            int cn = c + 1;
            for (int j = t; j < kM * kM * kNY; j += 256) {
                int y = j % kNY; int pq = j / kNY;
                float2 u = make_float2(0.f, 0.f);
                #pragma unroll
                for (int m = 0; m < kM; ++m)
                    cfma(u, o2s[cn * kMR + pq * kM + m], e3a[cn * (kM * kNY) + m * kNY + y]);
                UsD[cur ^ 1][j] = u;
            }
        }
        if (t < kNS) {
            float2 e2r[kM];
            #pragma unroll
            for (int q = 0; q < kM; ++q) e2r[q] = e2a[c * (kM * kNX) + q * kNX + xx];
            #pragma unroll
            for (int p = 0; p < kM; ++p) {
                float2 v = make_float2(0.f, 0.f);
                #pragma unroll
                for (int q = 0; q < kM; ++q)
                    cfma(v, UsD[cur][(p * kM + q) * kNY + yy], e2r[q]);
                const int e1base = (c * kM + p) * kNT;
                #pragma unroll
                for (int z = 0; z < kNT; ++z) {
                    float2 e = e1s[e1base + z];
                    accz[z] = fmaf(v.x, e.x, fmaf(-v.y, e.y, accz[z]));
                }
            }
        }
        __syncthreads();   // slot cur free for c+2's write; slot cur^1 ready
    }

    if (t < kNS) {
        const float sc = 1.0f / 7644.0f;
        size_t base = (size_t)bx * kNF + t;
        #pragma unroll
        for (int z = 0; z < kNT; ++z)
            outp[base + (size_t)z * kNS] = accz[z] * sc;
    }
}

// ---------------------------------------------------------------------------
extern "C" void kernel_launch(void* const* d_in, const int* in_sizes, int n_in,
                              void* d_out, int out_size, void* d_ws, size_t ws_size,
                              hipStream_t stream) {
    (void)in_sizes; (void)n_in; (void)out_size; (void)ws_size;
    const float* x      = (const float*)d_in[0];
    const float* wp1_re = (const float*)d_in[1];
    const float* wp1_im = (const float*)d_in[2];
    const float* wp2_re = (const float*)d_in[3];
    const float* wp2_im = (const float*)d_in[4];
    const float* wp3_re = (const float*)d_in[5];
    const float* wp3_im = (const float*)d_in[6];
    const float* wr_re  = (const float*)d_in[7];
    const float* wr_im  = (const float*)d_in[8];
    float* out = (float*)d_out;

    const size_t big = (size_t)kNIK * kNF;  // 1,956,864 complex
    float2* A   = (float2*)d_ws;            // scratch 1 (or1)
    float2* Bb  = A + big;                  // scratch 2 (alpha)
    float2* Cc  = Bb + big;                 // H, then or2 partials, then ifft scratch
    float2* OR2 = Cc + big;                 // 55,296
    float2* r1t = OR2 + (size_t)kB * kC * kMR;
    float2* r2t = r1t + (size_t)kNIK * kM * kNT;
    float2* r3t = r2t + (size_t)kNIK * kM * kNX;
    float2* e1t = r3t + (size_t)kNIK * kM * kNY;
    float2* e2t = e1t + (size_t)kNIK * kM * kNT;
    float2* e3t = e2t + (size_t)kNIK * kM * kNX;
    float2* F39 = e3t + (size_t)kNIK * kM * kNY;
    float2* F14 = F39 + kNT * kNT;

    k_init<<<64, 256, 0, stream>>>(wp1_re, wp1_im, wp2_re, wp2_im, wp3_re, wp3_im,
                                   F39, F14, r1t, r2t, r3t, e1t, e2t, e3t);
    // forward DFT: x -> A (t-pass) -> Bb (fused xy). alpha lives in Bb.
    k_dft_t_real<<<dim3(kNIK, 3), 256, 0, stream>>>(x, F39, A);
    k_dft_xy<<<kNIK * kNT, 256, 0, stream>>>(A, F14, Bb);
    // transfer function H -> Cc; or1 -> A
    k_H<<<kNIK, 256, 0, stream>>>(wr_re, wr_im, r1t, r2t, r3t, Cc);
    k_or1<<<kNF / kFCH, 256, 0, stream>>>(Bb, Cc, A);
    // or2: partials into Cc (H dead), reduce -> OR2. Last readers of alpha (Bb).
    k_or2p<<<(kB / 2) * kC * kC, 256, 0, stream>>>(Bb, wr_re, wr_im, r1t, r2t, r3t, Cc);
    k_or2red<<<(kB * kC * kMR + 255) / 256, 256, 0, stream>>>(Cc, OR2);
    // x2 -> d_out directly (overwrite; one block per (b,k), fully LDS-resident)
    k_x2f<<<kB * kC, 256, 0, stream>>>(OR2, e1t, e2t, e3t, out);
    // inverse FFT of or1 (in A): A -> Cc (t-pass) -> += d_out (fused xy + add)
    k_idft_t<<<dim3(kB * kC, 3), 256, 0, stream>>>(A, F39, Cc);
    k_idft_xy_final<<<kNIK * kNT, 256, 0, stream>>>(Cc, F14, out);
}

// Round 7
// 202.254 us; speedup vs baseline: 1.7420x; 1.0233x over previous
//
#include <hip/hip_runtime.h>

// Problem constants
constexpr int kB  = 16;    // batch
constexpr int kC  = 16;    // CI == CO
constexpr int kM  = 6;     // M1 == M2 == M3
constexpr int kNT = 39;
constexpr int kNX = 14;    // NXr
constexpr int kNY = 14;    // NYr
constexpr int kNS = kNX * kNY;       // 196
constexpr int kNF = kNT * kNS;       // 7644
constexpr int kNIK = kC * kC;        // 256
constexpr int kMR = kM * kM * kM;    // 216
constexpr int kFCH = 6;              // f-chunk for k_or1 (7644 = 6*1274)

__device__ __forceinline__ float2 cmul(float2 a, float2 b) {
    return make_float2(a.x * b.x - a.y * b.y, a.x * b.y + a.y * b.x);
}
__device__ __forceinline__ void cfma(float2& c, float2 a, float2 b) {
    c.x = fmaf(a.x, b.x, fmaf(-a.y, b.y, c.x));
    c.y = fmaf(a.x, b.y, fmaf(a.y, b.x, c.y));
}

// ---------------------------------------------------------------------------
// K0: DFT matrices + pole-reciprocal tables r1/r2/r3 + exp tables e1/e2/e3
// ---------------------------------------------------------------------------
__global__ __launch_bounds__(256) void k_init(
    const float* __restrict__ wp1_re, const float* __restrict__ wp1_im,
    const float* __restrict__ wp2_re, const float* __restrict__ wp2_im,
    const float* __restrict__ wp3_re, const float* __restrict__ wp3_im,
    float2* __restrict__ F39, float2* __restrict__ F14,
    float2* __restrict__ r1t, float2* __restrict__ r2t, float2* __restrict__ r3t,
    float2* __restrict__ e1t, float2* __restrict__ e2t, float2* __restrict__ e3t)
{
    const float PI2 = 6.283185307179586f;
    int tid = blockIdx.x * blockDim.x + threadIdx.x;
    int nth = gridDim.x * blockDim.x;

    for (int idx = tid; idx < kNT * kNT; idx += nth) {
        int m = idx / kNT, t = idx % kNT;
        float ang = -PI2 * (float)((m * t) % kNT) / (float)kNT;
        float s, c; sincosf(ang, &s, &c);
        F39[idx] = make_float2(c, s);
    }
    for (int idx = tid; idx < kNX * kNX; idx += nth) {
        int a = idx / kNX, b = idx % kNX;
        float ang = -PI2 * (float)((a * b) % kNX) / (float)kNX;
        float s, c; sincosf(ang, &s, &c);
        F14[idx] = make_float2(c, s);
    }
    for (int idx = tid; idx < kNIK * kM * kNT; idx += nth) {
        int z = idx % kNT; int ikp = idx / kNT;
        float wre = wp1_re[ikp], wim = wp1_im[ikp];
        float f = (z < 20 ? (float)z : (float)(z - kNT)) / (float)kNT;
        float w = PI2 * f;
        float dr = -wre, di = w - wim;
        float inv = 1.0f / (dr * dr + di * di);
        r1t[idx] = make_float2(dr * inv, -di * inv);
        float tt = (float)z;
        float er = expf(wre * tt);
        float s, c; sincosf(wim * tt, &s, &c);
        e1t[idx] = make_float2(er * c, er * s);
    }
    for (int idx = tid; idx < kNIK * kM * kNX; idx += nth) {
        int n = idx % kNX; int ikq = idx / kNX;
        float f = (n <= 6 ? (float)n : (float)(n - kNX)) * 27.0f / 14.0f;
        float w = PI2 * f;
        float tx = (float)n * (1.0f / 27.0f);
        {
            float wre = wp2_re[ikq], wim = wp2_im[ikq];
            float dr = -wre, di = w - wim;
            float inv = 1.0f / (dr * dr + di * di);
            r2t[idx] = make_float2(dr * inv, -di * inv);
            float er = expf(wre * tx);
            float s, c; sincosf(wim * tx, &s, &c);
            e2t[idx] = make_float2(er * c, er * s);
        }
        {
            float wre = wp3_re[ikq], wim = wp3_im[ikq];
            float dr = -wre, di = w - wim;
            float inv = 1.0f / (dr * dr + di * di);
            r3t[idx] = make_float2(dr * inv, -di * inv);
            float er = expf(wre * tx);
            float s, c; sincosf(wim * tx, &s, &c);
            e3t[idx] = make_float2(er * c, er * s);
        }
    }
}

// ---------------------------------------------------------------------------
// Forward t-DFT of real x, register-column form. grid (bc, 3); thread owns s.
// ---------------------------------------------------------------------------
__global__ __launch_bounds__(256) void k_dft_t_real(
    const float* __restrict__ x, const float2* __restrict__ F39, float2* __restrict__ out)
{
    int bc = blockIdx.x, mg = blockIdx.y;
    __shared__ float2 Fs[13 * kNT];
    int t = threadIdx.x;
    for (int j = t; j < 13 * kNT; j += 256)
        Fs[j] = F39[(mg * 13 + j / kNT) * kNT + (j % kNT)];
    __syncthreads();
    if (t < kNS) {
        float col[kNT];
        const float* xp = x + (size_t)bc * kNF + t;
        #pragma unroll
        for (int tt = 0; tt < kNT; ++tt) col[tt] = xp[(size_t)tt * kNS];
        for (int mi = 0; mi < 13; ++mi) {
            float2 acc = make_float2(0.f, 0.f);
            #pragma unroll
            for (int tt = 0; tt < kNT; ++tt) {
                float2 f = Fs[mi * kNT + tt];
                acc.x = fmaf(f.x, col[tt], acc.x);
                acc.y = fmaf(f.y, col[tt], acc.y);
            }
            out[((size_t)bc * kNT + mg * 13 + mi) * kNS + t] = acc;
        }
    }
}

// ---------------------------------------------------------------------------
// Inverse t-DFT (conj F), register-column form. grid (bk, 3); thread owns s.
// ---------------------------------------------------------------------------
__global__ __launch_bounds__(256) void k_idft_t(
    const float2* __restrict__ in, const float2* __restrict__ F39, float2* __restrict__ out)
{
    int bk = blockIdx.x, zg = blockIdx.y;
    __shared__ float2 Fs[13 * kNT];
    int t = threadIdx.x;
    for (int j = t; j < 13 * kNT; j += 256) {
        float2 f = F39[(zg * 13 + j / kNT) * kNT + (j % kNT)];
        f.y = -f.y;
        Fs[j] = f;
    }
    __syncthreads();
    if (t < kNS) {
        float2 col[kNT];
        const float2* ip = in + (size_t)bk * kNF + t;
        #pragma unroll
        for (int m = 0; m < kNT; ++m) col[m] = ip[(size_t)m * kNS];
        for (int zi = 0; zi < 13; ++zi) {
            float2 acc = make_float2(0.f, 0.f);
            #pragma unroll
            for (int m = 0; m < kNT; ++m) cfma(acc, Fs[zi * kNT + m], col[m]);
            out[((size_t)bk * kNT + zg * 13 + zi) * kNS + t] = acc;
        }
    }
}

// ---------------------------------------------------------------------------
// Fused forward x+y DFT on one 14x14 tile. Block per (bc*39+m).
// ---------------------------------------------------------------------------
__global__ __launch_bounds__(256) void k_dft_xy(
    const float2* __restrict__ in, const float2* __restrict__ F14, float2* __restrict__ out)
{
    int bm = blockIdx.x;
    __shared__ float2 tile[kNS];
    __shared__ float2 tmp[kNS];
    __shared__ float2 Fs[kNX * kNX];
    int t = threadIdx.x;
    if (t < kNS) tile[t] = in[(size_t)bm * kNS + t];
    if (t < kNX * kNX) Fs[t] = F14[t];
    __syncthreads();
    if (t < kNS) {
        int n2 = t / kNY, l = t % kNY;
        float2 acc = make_float2(0.f, 0.f);
        #pragma unroll
        for (int n = 0; n < kNX; ++n) cfma(acc, Fs[n2 * kNX + n], tile[n * kNY + l]);
        tmp[t] = acc;
    }
    __syncthreads();
    if (t < kNS) {
        int n = t / kNY, l2 = t % kNY;
        float2 acc = make_float2(0.f, 0.f);
        #pragma unroll
        for (int l = 0; l < kNY; ++l) cfma(acc, Fs[l2 * kNY + l], tmp[n * kNY + l]);
        out[(size_t)bm * kNS + t] = acc;
    }
}

// Fused inverse x+y DFT + take-real + scale + add into output.
__global__ __launch_bounds__(256) void k_idft_xy_final(
    const float2* __restrict__ in, const float2* __restrict__ F14, float* __restrict__ outp)
{
    int bm = blockIdx.x;
    __shared__ float2 tile[kNS];
    __shared__ float2 tmp[kNS];
    __shared__ float2 Fs[kNX * kNX];
    int t = threadIdx.x;
    if (t < kNS) tile[t] = in[(size_t)bm * kNS + t];
    if (t < kNX * kNX) { float2 f = F14[t]; f.y = -f.y; Fs[t] = f; }
    __syncthreads();
    if (t < kNS) {
        int n2 = t / kNY, l = t % kNY;
        float2 acc = make_float2(0.f, 0.f);
        #pragma unroll
        for (int n = 0; n < kNX; ++n) cfma(acc, Fs[n2 * kNX + n], tile[n * kNY + l]);
        tmp[t] = acc;
    }
    __syncthreads();
    if (t < kNS) {
        int n = t / kNY, l2 = t % kNY;
        float2 acc = make_float2(0.f, 0.f);
        #pragma unroll
        for (int l = 0; l < kNY; ++l) cfma(acc, Fs[l2 * kNY + l], tmp[n * kNY + l]);
        outp[(size_t)bm * kNS + t] += acc.x * (1.0f / 7644.0f);
    }
}

// ---------------------------------------------------------------------------
// K4: H[i,k,m,n,l] = sum_{p,q,r} wr[i,k,p,q,r] r1[m] r2[n] r3[l]; block per (i,k)
// ---------------------------------------------------------------------------
__global__ __launch_bounds__(256) void k_H(
    const float* __restrict__ wr_re, const float* __restrict__ wr_im,
    const float2* __restrict__ r1t, const float2* __restrict__ r2t,
    const float2* __restrict__ r3t, float2* __restrict__ H)
{
    int ik = blockIdx.x;
    __shared__ float2 wrs[kMR];
    __shared__ float2 r1s[kM * kNT];
    __shared__ float2 r2s[kM * kNX];
    __shared__ float2 r3s[kM * kNY];
    __shared__ float2 As[kM * kM * kNY];
    __shared__ float2 Ss[kM * kNS];
    int t = threadIdx.x;
    for (int j = t; j < kMR; j += 256)
        wrs[j] = make_float2(wr_re[ik * kMR + j], wr_im[ik * kMR + j]);
    for (int j = t; j < kM * kNT; j += 256) r1s[j] = r1t[(size_t)ik * kM * kNT + j];
    for (int j = t; j < kM * kNX; j += 256) r2s[j] = r2t[(size_t)ik * kM * kNX + j];
    for (int j = t; j < kM * kNY; j += 256) r3s[j] = r3t[(size_t)ik * kM * kNY + j];
    __syncthreads();
    for (int j = t; j < kM * kM * kNY; j += 256) {
        int l = j % kNY; int pq = j / kNY;
        float2 acc = make_float2(0.f, 0.f);
        #pragma unroll
        for (int r = 0; r < kM; ++r) cfma(acc, wrs[pq * kM + r], r3s[r * kNY + l]);
        As[j] = acc;
    }
    __syncthreads();
    for (int j = t; j < kM * kNS; j += 256) {
        int l = j % kNY; int n = (j / kNY) % kNX; int p = j / kNS;
        float2 acc = make_float2(0.f, 0.f);
        #pragma unroll
        for (int q = 0; q < kM; ++q) cfma(acc, r2s[q * kNX + n], As[(p * kM + q) * kNY + l]);
        Ss[j] = acc;
    }
    __syncthreads();
    for (int j = t; j < kNF; j += 256) {
        int m = j / kNS; int nl = j % kNS;
        float2 acc = make_float2(0.f, 0.f);
        #pragma unroll
        for (int p = 0; p < kM; ++p) cfma(acc, r1s[p * kNT + m], Ss[p * kNS + nl]);
        H[(size_t)ik * kNF + j] = acc;
    }
}

// ---------------------------------------------------------------------------
// K5: or1[b,k,f] = sum_i alpha[b,i,f] * H[i,k,f]
// f-chunked, LDS-staged (16x reuse). One block per 6 f's; thread = (b,k).
// ---------------------------------------------------------------------------
__global__ __launch_bounds__(256) void k_or1(
    const float2* __restrict__ alpha, const float2* __restrict__ H, float2* __restrict__ out)
{
    int f0 = blockIdx.x * kFCH;
    __shared__ float2 As[256 * 7 + 16];
    __shared__ float2 Hs[256 * 7 + 16];
    int t = threadIdx.x;
    {
        const float2* ap = alpha + (size_t)t * kNF + f0;
        const float2* hp = H + (size_t)t * kNF + f0;
        int base = t * 7 + (t >> 4);
        #pragma unroll
        for (int j = 0; j < kFCH; ++j) {
            As[base + j] = ap[j];
            Hs[base + j] = hp[j];
        }
    }
    __syncthreads();
    int b = t >> 4, k = t & 15;
    float2 acc[kFCH];
    #pragma unroll
    for (int j = 0; j < kFCH; ++j) acc[j] = make_float2(0.f, 0.f);
    #pragma unroll
    for (int i = 0; i < kC; ++i) {
        int ai = (b * 16 + i) * 7 + b;
        int hi = (i * 16 + k) * 7 + i;
        #pragma unroll
        for (int j = 0; j < kFCH; ++j) cfma(acc[j], As[ai + j], Hs[hi + j]);
    }
    float2* op = out + (size_t)t * kNF + f0;
    #pragma unroll
    for (int j = 0; j < kFCH; ++j) op[j] = acc[j];
}

// ---------------------------------------------------------------------------
// K7a: partial or2 per (b-pair,k,i). Tables (ik) amortized across 2 batches.
// P[((b*16+k)*16+i)*216+t] = wr[ik,t] * G[b,i,k,t]
// ---------------------------------------------------------------------------
__global__ __launch_bounds__(256) void k_or2p(
    const float2* __restrict__ alpha,
    const float* __restrict__ wr_re, const float* __restrict__ wr_im,
    const float2* __restrict__ r1t, const float2* __restrict__ r2t,
    const float2* __restrict__ r3t, float2* __restrict__ P)
{
    int blk = blockIdx.x;            // (pb*16 + k)*16 + i
    int i = blk % kC; int rest = blk / kC;
    int k = rest % kC; int pb = rest / kC;
    int b0 = 2 * pb, b1 = 2 * pb + 1;
    int ik = i * kC + k;
    __shared__ float2 r1s[kM * kNT];
    __shared__ float2 r2s[kM * kNX];
    __shared__ float2 r3s[kM * kNY];
    __shared__ float2 wrs[kMR];
    __shared__ float2 T1a[kM * kNS];
    __shared__ float2 T1b[kM * kNS];
    __shared__ float2 T2a[kM * kM * kNY];
    __shared__ float2 T2b[kM * kM * kNY];
    int t = threadIdx.x;
    for (int j = t; j < kM * kNT; j += 256) r1s[j] = r1t[(size_t)ik * kM * kNT + j];
    for (int j = t; j < kM * kNX; j += 256) r2s[j] = r2t[(size_t)ik * kM * kNX + j];
    for (int j = t; j < kM * kNY; j += 256) r3s[j] = r3t[(size_t)ik * kM * kNY + j];
    for (int j = t; j < kMR; j += 256)
        wrs[j] = make_float2(wr_re[ik * kMR + j], wr_im[ik * kMR + j]);
    __syncthreads();
    if (t < kNS) {
        float2 c0 = make_float2(0.f, 0.f), c1 = c0, c2 = c0, c3 = c0, c4 = c0, c5 = c0;
        float2 d0 = c0, d1 = c0, d2 = c0, d3 = c0, d4 = c0, d5 = c0;
        const float2* ap0 = alpha + (size_t)(b0 * kC + i) * kNF + t;
        const float2* ap1 = alpha + (size_t)(b1 * kC + i) * kNF + t;
        for (int m = 0; m < kNT; ++m) {
            float2 a0 = ap0[(size_t)m * kNS];
            float2 a1 = ap1[(size_t)m * kNS];
            float2 r;
            r = r1s[0 * kNT + m]; cfma(c0, a0, r); cfma(d0, a1, r);
            r = r1s[1 * kNT + m]; cfma(c1, a0, r); cfma(d1, a1, r);
            r = r1s[2 * kNT + m]; cfma(c2, a0, r); cfma(d2, a1, r);
            r = r1s[3 * kNT + m]; cfma(c3, a0, r); cfma(d3, a1, r);
            r = r1s[4 * kNT + m]; cfma(c4, a0, r); cfma(d4, a1, r);
            r = r1s[5 * kNT + m]; cfma(c5, a0, r); cfma(d5, a1, r);
        }
        T1a[0 * kNS + t] = c0; T1a[1 * kNS + t] = c1; T1a[2 * kNS + t] = c2;
        T1a[3 * kNS + t] = c3; T1a[4 * kNS + t] = c4; T1a[5 * kNS + t] = c5;
        T1b[0 * kNS + t] = d0; T1b[1 * kNS + t] = d1; T1b[2 * kNS + t] = d2;
        T1b[3 * kNS + t] = d3; T1b[4 * kNS + t] = d4; T1b[5 * kNS + t] = d5;
    }
    __syncthreads();
    for (int j = t; j < kM * kM * kNY; j += 256) {
        int l = j % kNY; int q = (j / kNY) % kM; int p = j / (kNY * kM);
        float2 a2 = make_float2(0.f, 0.f);
        float2 b2 = make_float2(0.f, 0.f);
        #pragma unroll
        for (int n = 0; n < kNX; ++n) {
            float2 r = r2s[q * kNX + n];
            cfma(a2, T1a[p * kNS + n * kNY + l], r);
            cfma(b2, T1b[p * kNS + n * kNY + l], r);
        }
        T2a[j] = a2;
        T2b[j] = b2;
    }
    __syncthreads();
    if (t < kMR) {
        int r = t % kM; int q = (t / kM) % kM; int p = t / (kM * kM);
        float2 t3a = make_float2(0.f, 0.f);
        float2 t3b = make_float2(0.f, 0.f);
        #pragma unroll
        for (int l = 0; l < kNY; ++l) {
            float2 rr = r3s[r * kNY + l];
            cfma(t3a, T2a[(p * kM + q) * kNY + l], rr);
            cfma(t3b, T2b[(p * kM + q) * kNY + l], rr);
        }
        float2 w = wrs[t];
        P[((size_t)(b0 * kC + k) * kC + i) * kMR + t] = cmul(w, t3a);
        P[((size_t)(b1 * kC + k) * kC + i) * kMR + t] = cmul(w, t3b);
    }
}

// K7b: or2[bk][t] = -sum_i P[(bk*16+i)*216+t]
__global__ __launch_bounds__(256) void k_or2red(
    const float2* __restrict__ P, float2* __restrict__ or2)
{
    int id = blockIdx.x * blockDim.x + threadIdx.x;
    if (id >= kB * kC * kMR) return;
    int t = id % kMR; int bk = id / kMR;
    float2 s = make_float2(0.f, 0.f);
    #pragma unroll
    for (int i = 0; i < kC; ++i) {
        float2 v = P[((size_t)bk * kC + i) * kMR + t];
        s.x += v.x; s.y += v.y;
    }
    or2[id] = make_float2(-s.x, -s.y);
}

// ---------------------------------------------------------------------------
// K8: x2 as register-tiled GEMM. One block per (b,k), 256 threads.
// x2[z,s] = Re( e1[39x96] @ V[96x196] ), K=(c,p); V computed per-c in LDS
// (double-buffered), Us(c+1) overlapped with GEMM(c). Thread = (zt=t>>6,
// sl=t&63) owns 10z x 4s tile: per K-step 10 broadcast e1 reads + 4
// coalesced V reads + 80 FMA.
// ---------------------------------------------------------------------------
__global__ __launch_bounds__(256) void k_x2g(
    const float2* __restrict__ or2,
    const float2* __restrict__ e1t, const float2* __restrict__ e2t,
    const float2* __restrict__ e3t, float* __restrict__ outp)
{
    int bx = blockIdx.x;
    int k = bx & 15, b = bx >> 4;
    __shared__ float2 o2s[kC * kMR];          // [c][pq*6+m]   27648 B
    __shared__ float2 e1s[kC * kM * 40];      // [c][p][z pad40] 30720 B
    __shared__ float2 e2a[kC * kM * kNX];     // [c][q][x]     10752 B
    __shared__ float2 e3a[kC * kM * kNY];     // [c][m][y]     10752 B
    __shared__ float2 Us[kM * kM * kNY];      // [p][q][y]      4032 B
    __shared__ float2 Vb[2][kM * 200];        // [p][s pad200] 19200 B
    int t = threadIdx.x;
    int sl = t & 63;        // s-lane
    int zt = t >> 6;        // z-offset 0..3

    // stage all tables once (coalesced)
    for (int j = t; j < kC * kMR; j += 256) {
        int c = j / kMR, u = j % kMR;
        o2s[j] = or2[(size_t)(b * kC + c) * kMR + u];
    }
    for (int j = t; j < kC * kM * kNT; j += 256) {
        int c = j / (kM * kNT), r = j % (kM * kNT);
        int p = r / kNT, z = r % kNT;
        e1s[(c * kM + p) * 40 + z] = e1t[(size_t)(c * kC + k) * (kM * kNT) + r];
    }
    for (int j = t; j < kC * kM; j += 256)
        e1s[j * 40 + 39] = make_float2(0.f, 0.f);   // zero pad slot
    for (int j = t; j < kC * kM * kNX; j += 256) {
        int c = j / (kM * kNX), r = j % (kM * kNX);
        e2a[j] = e2t[(size_t)(c * kC + k) * (kM * kNX) + r];
    }
    for (int j = t; j < kC * kM * kNY; j += 256) {
        int c = j / (kM * kNY), r = j % (kM * kNY);
        e3a[j] = e3t[(size_t)(c * kC + k) * (kM * kNY) + r];
    }
    __syncthreads();

    // Us(0): Us[p,q,y] = sum_m o2[c=0,p,q,m] * e3[c=0,m,y]
    for (int j = t; j < kM * kM * kNY; j += 256) {
        int y = j % kNY, pq = j / kNY;
        float2 u = make_float2(0.f, 0.f);
        #pragma unroll
        for (int m = 0; m < kM; ++m)
            cfma(u, o2s[pq * kM + m], e3a[m * kNY + y]);
        Us[j] = u;
    }
    __syncthreads();
    // V(0) -> slot 0: V[p,s] = sum_q Us[p,q,y] * e2[c=0,q,x]
    for (int j = t; j < kM * 200; j += 256) {
        int p = j / 200, s = j % 200;
        float2 v = make_float2(0.f, 0.f);
        if (s < kNS) {
            int x = s / kNY, y = s % kNY;
            #pragma unroll
            for (int q = 0; q < kM; ++q)
                cfma(v, Us[(p * kM + q) * kNY + y], e2a[q * kNX + x]);
        }
        Vb[0][j] = v;
    }
    __syncthreads();

    float accz[10][4];
    #pragma unroll
    for (int zi = 0; zi < 10; ++zi)
        #pragma unroll
        for (int j = 0; j < 4; ++j) accz[zi][j] = 0.f;

    for (int c = 0; c < kC; ++c) {
        int cur = c & 1;
        // Us(c+1): writes Us; GEMM(c) reads Vb[cur]/e1s — disjoint, same phase
        if (c + 1 < kC) {
            int cn = c + 1;
            for (int j = t; j < kM * kM * kNY; j += 256) {
                int y = j % kNY, pq = j / kNY;
                float2 u = make_float2(0.f, 0.f);
                #pragma unroll
                for (int m = 0; m < kM; ++m)
                    cfma(u, o2s[cn * kMR + pq * kM + m],
                            e3a[cn * (kM * kNY) + m * kNY + y]);
                Us[j] = u;
            }
        }
        // GEMM(c): accz[zi][j] += Re(V[p][sl+64j] * e1[c,p,zt+4zi])
        #pragma unroll
        for (int p = 0; p < kM; ++p) {
            float2 vr[4];
            #pragma unroll
            for (int j = 0; j < 4; ++j) vr[j] = Vb[cur][p * 200 + sl + 64 * j];
            const int e1base = (c * kM + p) * 40 + zt;
            #pragma unroll
            for (int zi = 0; zi < 10; ++zi) {
                float2 e = e1s[e1base + 4 * zi];
                #pragma unroll
                for (int j = 0; j < 4; ++j)
                    accz[zi][j] = fmaf(vr[j].x, e.x, fmaf(-vr[j].y, e.y, accz[zi][j]));
            }
        }
        __syncthreads();
        // V(c+1) -> other slot (reads the Us just built)
        if (c + 1 < kC) {
            int cn = c + 1;
            for (int j = t; j < kM * 200; j += 256) {
                int p = j / 200, s = j % 200;
                float2 v = make_float2(0.f, 0.f);
                if (s < kNS) {
                    int x = s / kNY, y = s % kNY;
                    #pragma unroll
                    for (int q = 0; q < kM; ++q)
                        cfma(v, Us[(p * kM + q) * kNY + y],
                                e2a[cn * (kM * kNX) + q * kNX + x]);
                }
                Vb[cur ^ 1][j] = v;
            }
        }
        __syncthreads();
    }

    const float sc = 1.0f / 7644.0f;
    size_t base = (size_t)bx * kNF;
    #pragma unroll
    for (int zi = 0; zi < 10; ++zi) {
        int z = zt + 4 * zi;
        if (z < kNT) {
            #pragma unroll
            for (int j = 0; j < 4; ++j) {
                int s = sl + 64 * j;
                if (s < kNS)
                    outp[base + (size_t)z * kNS + s] = accz[zi][j] * sc;
            }
        }
    }
}

// ---------------------------------------------------------------------------
extern "C" void kernel_launch(void* const* d_in, const int* in_sizes, int n_in,
                              void* d_out, int out_size, void* d_ws, size_t ws_size,
                              hipStream_t stream) {
    (void)in_sizes; (void)n_in; (void)out_size; (void)ws_size;
    const float* x      = (const float*)d_in[0];
    const float* wp1_re = (const float*)d_in[1];
    const float* wp1_im = (const float*)d_in[2];
    const float* wp2_re = (const float*)d_in[3];
    const float* wp2_im = (const float*)d_in[4];
    const float* wp3_re = (const float*)d_in[5];
    const float* wp3_im = (const float*)d_in[6];
    const float* wr_re  = (const float*)d_in[7];
    const float* wr_im  = (const float*)d_in[8];
    float* out = (float*)d_out;

    const size_t big = (size_t)kNIK * kNF;  // 1,956,864 complex
    float2* A   = (float2*)d_ws;            // scratch 1 (or1)
    float2* Bb  = A + big;                  // scratch 2 (alpha)
    float2* Cc  = Bb + big;                 // H, then or2 partials, then ifft scratch
    float2* OR2 = Cc + big;                 // 55,296
    float2* r1t = OR2 + (size_t)kB * kC * kMR;
    float2* r2t = r1t + (size_t)kNIK * kM * kNT;
    float2* r3t = r2t + (size_t)kNIK * kM * kNX;
    float2* e1t = r3t + (size_t)kNIK * kM * kNY;
    float2* e2t = e1t + (size_t)kNIK * kM * kNT;
    float2* e3t = e2t + (size_t)kNIK * kM * kNX;
    float2* F39 = e3t + (size_t)kNIK * kM * kNY;
    float2* F14 = F39 + kNT * kNT;

    k_init<<<64, 256, 0, stream>>>(wp1_re, wp1_im, wp2_re, wp2_im, wp3_re, wp3_im,
                                   F39, F14, r1t, r2t, r3t, e1t, e2t, e3t);
    // forward DFT: x -> A (t-pass) -> Bb (fused xy). alpha lives in Bb.
    k_dft_t_real<<<dim3(kNIK, 3), 256, 0, stream>>>(x, F39, A);
    k_dft_xy<<<kNIK * kNT, 256, 0, stream>>>(A, F14, Bb);
    // transfer function H -> Cc; or1 -> A
    k_H<<<kNIK, 256, 0, stream>>>(wr_re, wr_im, r1t, r2t, r3t, Cc);
    k_or1<<<kNF / kFCH, 256, 0, stream>>>(Bb, Cc, A);
    // or2: partials into Cc (H dead), reduce -> OR2. Last readers of alpha (Bb).
    k_or2p<<<(kB / 2) * kC * kC, 256, 0, stream>>>(Bb, wr_re, wr_im, r1t, r2t, r3t, Cc);
    k_or2red<<<(kB * kC * kMR + 255) / 256, 256, 0, stream>>>(Cc, OR2);
    // x2 -> d_out directly (overwrite; one block per (b,k), GEMM-tiled)
    k_x2g<<<kB * kC, 256, 0, stream>>>(OR2, e1t, e2t, e3t, out);
    // inverse FFT of or1 (in A): A -> Cc (t-pass) -> += d_out (fused xy + add)
    k_idft_t<<<dim3(kB * kC, 3), 256, 0, stream>>>(A, F39, Cc);
    k_idft_xy_final<<<kNIK * kNT, 256, 0, stream>>>(Cc, F14, out);
}